// Round 1
// baseline (7074.137 us; speedup 1.0000x reference)
//
#include <hip/hip_runtime.h>
#include <hip/hip_bf16.h>
#include <math.h>

// ---------------------------------------------------------------------------
// GNN on a fixed 4-node graph, B=32768.
// Strategy: aggregation matrices (4x4) precomputed once; every layer becomes
// node-mix (4x4) + dense GEMM over M = Bs*4 rows. fp32 correctness baseline.
// ---------------------------------------------------------------------------

// ---------- setup: build A_gcn (gmat[0..15]) and M_sage (gmat[16..31]) -----
__global__ void k_setup(const int* __restrict__ ei, float* __restrict__ gmat) {
    if (threadIdx.x != 0 || blockIdx.x != 0) return;
    // detect int64 vs int32 storage of edge_index [2][12]
    bool is64 = true;
    for (int i = 0; i < 12; i++) if (ei[2 * i + 1] != 0) { is64 = false; break; }
    int src[12], dst[12];
    for (int e = 0; e < 12; e++) {
        if (is64) { src[e] = ei[2 * e]; dst[e] = ei[24 + 2 * e]; }
        else      { src[e] = ei[e];     dst[e] = ei[12 + e]; }
    }
    // GCN: deg includes self loops
    float deg[4] = {1.f, 1.f, 1.f, 1.f};
    for (int e = 0; e < 12; e++) deg[dst[e]] += 1.f;
    float dinv[4];
    for (int n = 0; n < 4; n++) dinv[n] = 1.f / sqrtf(deg[n]);
    float A[16];
    for (int i = 0; i < 16; i++) A[i] = 0.f;
    for (int e = 0; e < 12; e++) A[dst[e] * 4 + src[e]] += dinv[src[e]] * dinv[dst[e]];
    for (int n = 0; n < 4; n++) A[n * 4 + n] += dinv[n] * dinv[n];
    // SAGE mean matrix
    float cnt[4] = {0.f, 0.f, 0.f, 0.f};
    for (int e = 0; e < 12; e++) cnt[dst[e]] += 1.f;
    for (int n = 0; n < 4; n++) cnt[n] = fmaxf(cnt[n], 1.f);
    float Mm[16];
    for (int i = 0; i < 16; i++) Mm[i] = 0.f;
    for (int e = 0; e < 12; e++) Mm[dst[e] * 4 + src[e]] += 1.f;
    for (int n = 0; n < 4; n++)
        for (int m = 0; m < 4; m++) Mm[n * 4 + m] /= cnt[n];
    for (int i = 0; i < 16; i++) { gmat[i] = A[i]; gmat[16 + i] = Mm[i]; }
}

// ---------- node-mix: out[(e,n),k] = sum_m mat[n,m] * h[(e,m),k] -----------
__global__ __launch_bounds__(256) void agg_mix(const float4* __restrict__ h,
                                               float4* __restrict__ out,
                                               const float* __restrict__ gmat,
                                               int K4) {
    int i = blockIdx.x * 256 + threadIdx.x;
    int kv = i % K4;
    int rn = i / K4;
    int n = rn & 3;
    const float4* base = h + (size_t)(rn & ~3) * K4 + kv;
    float m0 = gmat[n * 4 + 0], m1 = gmat[n * 4 + 1];
    float m2 = gmat[n * 4 + 2], m3 = gmat[n * 4 + 3];
    float4 v0 = base[0], v1 = base[K4], v2 = base[2 * (size_t)K4], v3 = base[3 * (size_t)K4];
    float4 r;
    r.x = m0 * v0.x + m1 * v1.x + m2 * v2.x + m3 * v3.x;
    r.y = m0 * v0.y + m1 * v1.y + m2 * v2.y + m3 * v3.y;
    r.z = m0 * v0.z + m1 * v1.z + m2 * v2.z + m3 * v3.z;
    r.w = m0 * v0.w + m1 * v1.w + m2 * v2.w + m3 * v3.w;
    out[i] = r;
}

// ---------- GEMM: out[M,N] = [A0|A1] @ [B0;B1] + bias, optional ReLU -------
// Tile: 64 rows x 256 cols, KC=8. 256 threads, micro-tile 4 rows x 16 cols.
__global__ __launch_bounds__(256) void gemm_kernel(
    const float* __restrict__ A0, int K0,
    const float* __restrict__ A1, int K1,
    const float* __restrict__ B0, const float* __restrict__ B1,
    const float* __restrict__ bias, float* __restrict__ out,
    int N, int relu) {
    __shared__ float As[8][64];
    __shared__ float Bsh[8][256];
    int t = threadIdx.x;
    int row0 = blockIdx.x * 64;
    int col0 = blockIdx.y * 256;
    int ttx = t & 15;        // -> 4-col group base, cols ttx*4 + cv*64
    int tty = t >> 4;        // -> rows tty*4 .. +3
    float4 acc[4][4];
#pragma unroll
    for (int i = 0; i < 4; i++)
#pragma unroll
        for (int j = 0; j < 4; j++) acc[i][j] = make_float4(0.f, 0.f, 0.f, 0.f);

    int Ktot = K0 + K1;
    int ar = t >> 1;            // A stage: row (t<128)
    int ak = (t & 1) * 4;       // A stage: k offset
    int bc = (t & 63) * 4;      // B stage: col
    int bk = t >> 6;            // B stage: k row 0..3 (and +4)

    for (int kb = 0; kb < Ktot; kb += 8) {
        if (kb) __syncthreads();
        if (t < 128) {
            const float* Ap; int stride, krel;
            if (kb < K0) { Ap = A0; stride = K0; krel = kb; }
            else         { Ap = A1; stride = K1; krel = kb - K0; }
            float4 ga = *(const float4*)&Ap[(size_t)(row0 + ar) * stride + krel + ak];
            As[ak + 0][ar] = ga.x; As[ak + 1][ar] = ga.y;
            As[ak + 2][ar] = ga.z; As[ak + 3][ar] = ga.w;
        }
        {
            const float* Bp; int krel;
            if (kb < K0) { Bp = B0; krel = kb; }
            else         { Bp = B1; krel = kb - K0; }
            *(float4*)&Bsh[bk][bc] =
                *(const float4*)&Bp[(size_t)(krel + bk) * N + col0 + bc];
            *(float4*)&Bsh[bk + 4][bc] =
                *(const float4*)&Bp[(size_t)(krel + bk + 4) * N + col0 + bc];
        }
        __syncthreads();
#pragma unroll
        for (int kk = 0; kk < 8; kk++) {
            float4 a = *(float4*)&As[kk][tty * 4];
            float4 b0 = *(float4*)&Bsh[kk][ttx * 4];
            float4 b1 = *(float4*)&Bsh[kk][ttx * 4 + 64];
            float4 b2 = *(float4*)&Bsh[kk][ttx * 4 + 128];
            float4 b3 = *(float4*)&Bsh[kk][ttx * 4 + 192];
            const float* av = (const float*)&a;
#pragma unroll
            for (int ri = 0; ri < 4; ri++) {
                float aa = av[ri];
                acc[ri][0].x += aa * b0.x; acc[ri][0].y += aa * b0.y;
                acc[ri][0].z += aa * b0.z; acc[ri][0].w += aa * b0.w;
                acc[ri][1].x += aa * b1.x; acc[ri][1].y += aa * b1.y;
                acc[ri][1].z += aa * b1.z; acc[ri][1].w += aa * b1.w;
                acc[ri][2].x += aa * b2.x; acc[ri][2].y += aa * b2.y;
                acc[ri][2].z += aa * b2.z; acc[ri][2].w += aa * b2.w;
                acc[ri][3].x += aa * b3.x; acc[ri][3].y += aa * b3.y;
                acc[ri][3].z += aa * b3.z; acc[ri][3].w += aa * b3.w;
            }
        }
    }
    // epilogue: bias (+ReLU), store
#pragma unroll
    for (int cv = 0; cv < 4; cv++) {
        int c = col0 + ttx * 4 + cv * 64;
        float4 bs = *(const float4*)&bias[c];
#pragma unroll
        for (int ri = 0; ri < 4; ri++) {
            float4 v = acc[ri][cv];
            v.x += bs.x; v.y += bs.y; v.z += bs.z; v.w += bs.w;
            if (relu) {
                v.x = fmaxf(v.x, 0.f); v.y = fmaxf(v.y, 0.f);
                v.z = fmaxf(v.z, 0.f); v.w = fmaxf(v.w, 0.f);
            }
            *(float4*)&out[(size_t)(row0 + tty * 4 + ri) * N + c] = v;
        }
    }
}

// ---------- row L2-normalize (pre-relu norm) then ReLU, in place -----------
__global__ __launch_bounds__(256) void norm_relu(float4* __restrict__ h, int F4) {
    int wid = threadIdx.x >> 6;
    int lane = threadIdx.x & 63;
    int row = blockIdx.x * 4 + wid;
    float4* p = h + (size_t)row * F4;
    float ss = 0.f;
    for (int j = lane; j < F4; j += 64) {
        float4 v = p[j];
        ss += v.x * v.x + v.y * v.y + v.z * v.z + v.w * v.w;
    }
    ss += __shfl_xor(ss, 32); ss += __shfl_xor(ss, 16); ss += __shfl_xor(ss, 8);
    ss += __shfl_xor(ss, 4);  ss += __shfl_xor(ss, 2);  ss += __shfl_xor(ss, 1);
    float s = sqrtf(ss);
    float inv = 1.f / fmaxf(s, 1e-12f);
    for (int j = lane; j < F4; j += 64) {
        float4 v = p[j];
        v.x = fmaxf(v.x * inv, 0.f); v.y = fmaxf(v.y * inv, 0.f);
        v.z = fmaxf(v.z * inv, 0.f); v.w = fmaxf(v.w * inv, 0.f);
        p[j] = v;
    }
}

// ---------- final FC (1024 -> 10) + softmax; one wave per batch element ----
__global__ __launch_bounds__(256) void fc_softmax(const float4* __restrict__ h4,
                                                  const float* __restrict__ Wfc,
                                                  const float* __restrict__ bfc,
                                                  float* __restrict__ outp) {
    __shared__ float WT[10][1024];   // 40 KB, transposed for conflict-free reads
    int t = threadIdx.x;
    for (int i = t; i < 10240; i += 256) {
        int o = i % 10, k = i / 10;
        WT[o][k] = Wfc[i];
    }
    __syncthreads();
    int wid = t >> 6, lane = t & 63;
    int e = blockIdx.x * 4 + wid;
    const float4* hp = h4 + (size_t)e * 256;   // 1024 floats per element
    float acc[10];
#pragma unroll
    for (int o = 0; o < 10; o++) acc[o] = 0.f;
#pragma unroll
    for (int j = 0; j < 4; j++) {
        int k4 = j * 64 + lane;
        float4 v = hp[k4];
#pragma unroll
        for (int o = 0; o < 10; o++) {
            float4 w = *(float4*)&WT[o][k4 * 4];
            acc[o] += v.x * w.x + v.y * w.y + v.z * w.z + v.w * w.w;
        }
    }
#pragma unroll
    for (int o = 0; o < 10; o++) {
        float v = acc[o];
        v += __shfl_xor(v, 32); v += __shfl_xor(v, 16); v += __shfl_xor(v, 8);
        v += __shfl_xor(v, 4);  v += __shfl_xor(v, 2);  v += __shfl_xor(v, 1);
        acc[o] = v + bfc[o];
    }
    float mx = acc[0];
#pragma unroll
    for (int o = 1; o < 10; o++) mx = fmaxf(mx, acc[o]);
    float sum = 0.f;
    float p[10];
#pragma unroll
    for (int o = 0; o < 10; o++) { p[o] = expf(acc[o] - mx); sum += p[o]; }
    float inv = 1.f / sum;
    if (lane < 10) outp[(size_t)e * 10 + lane] = p[lane] * inv;
}

// ---------------------------------------------------------------------------
extern "C" void kernel_launch(void* const* d_in, const int* in_sizes, int n_in,
                              void* d_out, int out_size, void* d_ws, size_t ws_size,
                              hipStream_t stream) {
    const float* x   = (const float*)d_in[0];
    const int*   ei  = (const int*)d_in[1];
    const float* W1  = (const float*)d_in[2];
    const float* b1  = (const float*)d_in[3];
    const float* Wl2 = (const float*)d_in[4];
    const float* bl2 = (const float*)d_in[5];
    const float* Wr2 = (const float*)d_in[6];
    const float* Wl3 = (const float*)d_in[7];
    const float* bl3 = (const float*)d_in[8];
    const float* Wr3 = (const float*)d_in[9];
    const float* Wl4 = (const float*)d_in[10];
    const float* bl4 = (const float*)d_in[11];
    const float* Wr4 = (const float*)d_in[12];
    const float* Wfc = (const float*)d_in[13];
    const float* bfc = (const float*)d_in[14];
    float* out = (float*)d_out;

    const int B = 32768;
    // per-element ws floats: h1 4096 + agg 4096 + h2 2048 + h3 1024 + h4 1024
    int Bs = B;
    while (Bs > 64 && (size_t)256 + (size_t)Bs * 49152 > ws_size) Bs >>= 1;
    int nslice = B / Bs;
    int M = Bs * 4;

    float* gmat = (float*)d_ws;
    float* h1  = gmat + 64;
    float* agg = h1  + (size_t)Bs * 4096;
    float* h2  = agg + (size_t)Bs * 4096;
    float* h3  = h2  + (size_t)Bs * 2048;
    float* h4  = h3  + (size_t)Bs * 1024;

    hipLaunchKernelGGL(k_setup, dim3(1), dim3(64), 0, stream, ei, gmat);

    for (int s = 0; s < nslice; s++) {
        const float* xs = x + (size_t)s * Bs * 256;
        // L1: GCN  (aggregate-first, then GEMM 64->1024, bias+ReLU fused)
        hipLaunchKernelGGL(agg_mix, dim3(Bs / 4), dim3(256), 0, stream,
                           (const float4*)xs, (float4*)agg, gmat, 16);
        hipLaunchKernelGGL(gemm_kernel, dim3(M / 64, 4), dim3(256), 0, stream,
                           agg, 64, (const float*)nullptr, 0, W1, (const float*)nullptr,
                           b1, h1, 1024, 1);
        // L2: SAGE 1024->512
        hipLaunchKernelGGL(agg_mix, dim3(Bs * 4), dim3(256), 0, stream,
                           (const float4*)h1, (float4*)agg, gmat + 16, 256);
        hipLaunchKernelGGL(gemm_kernel, dim3(M / 64, 2), dim3(256), 0, stream,
                           agg, 1024, h1, 1024, Wl2, Wr2, bl2, h2, 512, 0);
        hipLaunchKernelGGL(norm_relu, dim3(Bs), dim3(256), 0, stream, (float4*)h2, 128);
        // L3: SAGE 512->256
        hipLaunchKernelGGL(agg_mix, dim3(Bs * 2), dim3(256), 0, stream,
                           (const float4*)h2, (float4*)agg, gmat + 16, 128);
        hipLaunchKernelGGL(gemm_kernel, dim3(M / 64, 1), dim3(256), 0, stream,
                           agg, 512, h2, 512, Wl3, Wr3, bl3, h3, 256, 0);
        hipLaunchKernelGGL(norm_relu, dim3(Bs), dim3(256), 0, stream, (float4*)h3, 64);
        // L4: SAGE 256->256
        hipLaunchKernelGGL(agg_mix, dim3(Bs), dim3(256), 0, stream,
                           (const float4*)h3, (float4*)agg, gmat + 16, 64);
        hipLaunchKernelGGL(gemm_kernel, dim3(M / 64, 1), dim3(256), 0, stream,
                           agg, 256, h3, 256, Wl4, Wr4, bl4, h4, 256, 0);
        hipLaunchKernelGGL(norm_relu, dim3(Bs), dim3(256), 0, stream, (float4*)h4, 64);
        // FC + softmax
        hipLaunchKernelGGL(fc_softmax, dim3(Bs / 4), dim3(256), 0, stream,
                           (const float4*)h4, Wfc, bfc, out + (size_t)s * Bs * 10);
    }
}

// Round 3
// 1503.385 us; speedup vs baseline: 4.7055x; 4.7055x over previous
//
#include <hip/hip_runtime.h>
#include <stdint.h>
#include <math.h>

typedef __bf16 bf16;
typedef __attribute__((ext_vector_type(8))) __bf16 bf16x8;
typedef __attribute__((ext_vector_type(4))) float f32x4;

#define AS1 __attribute__((address_space(1)))
#define AS3 __attribute__((address_space(3)))

__device__ __forceinline__ void glds16(const void* g, void* l) {
    __builtin_amdgcn_global_load_lds((const AS1 uint32_t*)g, (AS3 uint32_t*)l, 16, 0, 0);
}

// ---------- setup: A_gcn (gmat[0..15]) and M_sage (gmat[16..31]) -----------
__global__ void k_setup(const int* __restrict__ ei, float* __restrict__ gmat) {
    if (threadIdx.x != 0 || blockIdx.x != 0) return;
    bool is64 = true;
    for (int i = 0; i < 12; i++) if (ei[2 * i + 1] != 0) { is64 = false; break; }
    int src[12], dst[12];
    for (int e = 0; e < 12; e++) {
        if (is64) { src[e] = ei[2 * e]; dst[e] = ei[24 + 2 * e]; }
        else      { src[e] = ei[e];     dst[e] = ei[12 + e]; }
    }
    float deg[4] = {1.f, 1.f, 1.f, 1.f};
    for (int e = 0; e < 12; e++) deg[dst[e]] += 1.f;
    float dinv[4];
    for (int n = 0; n < 4; n++) dinv[n] = 1.f / sqrtf(deg[n]);
    float A[16];
    for (int i = 0; i < 16; i++) A[i] = 0.f;
    for (int e = 0; e < 12; e++) A[dst[e] * 4 + src[e]] += dinv[src[e]] * dinv[dst[e]];
    for (int n = 0; n < 4; n++) A[n * 4 + n] += dinv[n] * dinv[n];
    float cnt[4] = {0.f, 0.f, 0.f, 0.f};
    for (int e = 0; e < 12; e++) cnt[dst[e]] += 1.f;
    for (int n = 0; n < 4; n++) cnt[n] = fmaxf(cnt[n], 1.f);
    float Mm[16];
    for (int i = 0; i < 16; i++) Mm[i] = 0.f;
    for (int e = 0; e < 12; e++) Mm[dst[e] * 4 + src[e]] += 1.f;
    for (int n = 0; n < 4; n++)
        for (int m = 0; m < 4; m++) Mm[n * 4 + m] /= cnt[n];
    for (int i = 0; i < 16; i++) { gmat[i] = A[i]; gmat[16 + i] = Mm[i]; }
}

// ---------- weight transpose+stack to bf16: Wt[n*Kt+k] = W{0|1}[k][n] ------
__global__ __launch_bounds__(256) void wtrans(const float* __restrict__ W0, int K0,
                                              const float* __restrict__ W1, int K1,
                                              int N, bf16* __restrict__ Wt) {
    int Kt = K0 + K1;
    int idx = blockIdx.x * 256 + threadIdx.x;
    if (idx >= N * Kt) return;
    int n = idx / Kt, k = idx - n * Kt;
    float v = (k < K0) ? W0[(size_t)k * N + n] : W1[(size_t)(k - K0) * N + n];
    Wt[idx] = (bf16)v;
}

// ---------- GCN aggregate on fp32 x -> bf16 [M,64] -------------------------
__global__ __launch_bounds__(256) void agg_x(const float4* __restrict__ x,
                                             bf16x8* __restrict__ out,
                                             const float* __restrict__ gm) {
    int i = blockIdx.x * 256 + threadIdx.x;   // over M*8 chunks (K=64 -> 8 chunks)
    int kv = i & 7; int rn = i >> 3; int n = rn & 3;
    const float4* base = x + (size_t)(rn & ~3) * 16 + kv * 2;
    float w[4] = {gm[n * 4], gm[n * 4 + 1], gm[n * 4 + 2], gm[n * 4 + 3]};
    float4 va[4][2];
#pragma unroll
    for (int m = 0; m < 4; m++) { va[m][0] = base[m * 16]; va[m][1] = base[m * 16 + 1]; }
    bf16x8 o;
#pragma unroll
    for (int c = 0; c < 8; c++) {
        int h = c >> 2, cc = c & 3;
        float s = 0.f;
#pragma unroll
        for (int m = 0; m < 4; m++) s += w[m] * ((const float*)&va[m][h])[cc];
        o[c] = (bf16)s;
    }
    out[i] = o;
}

// ---------- SAGE mean aggregate, bf16 -> bf16 ------------------------------
__global__ __launch_bounds__(256) void agg_b(const bf16x8* __restrict__ h,
                                             bf16x8* __restrict__ out,
                                             const float* __restrict__ gm, int K8) {
    int i = blockIdx.x * 256 + threadIdx.x;
    int kv = i % K8; int rn = i / K8; int n = rn & 3;
    const bf16x8* base = h + (size_t)(rn & ~3) * K8 + kv;
    float w0 = gm[n * 4], w1 = gm[n * 4 + 1], w2 = gm[n * 4 + 2], w3 = gm[n * 4 + 3];
    bf16x8 v0 = base[0], v1 = base[K8], v2 = base[2 * (size_t)K8], v3 = base[3 * (size_t)K8];
    bf16x8 o;
#pragma unroll
    for (int c = 0; c < 8; c++) {
        float s = w0 * (float)v0[c] + w1 * (float)v1[c] + w2 * (float)v2[c] + w3 * (float)v3[c];
        o[c] = (bf16)s;
    }
    out[i] = o;
}

// ---------- MFMA GEMM: out[M,N] = [A0|A1] @ Bt^T + bias (opt ReLU), bf16 ---
// Bt is [N, K0+K1] row-major (pre-transposed weights). 128x128 tile, BK=32.
// LDS holds fragments in MFMA lane order -> ds_read_b128 is linear (0 conflicts).
__global__ __launch_bounds__(256) void gemm_mfma(
    const bf16* __restrict__ A0, int K0,
    const bf16* __restrict__ A1, int K1,
    const bf16* __restrict__ Bt,
    const float* __restrict__ bias,
    bf16* __restrict__ out, int N, int relu) {
    __shared__ bf16 sA[4096];   // 8 frags x 512 elems (16 rows x 32 k)
    __shared__ bf16 sB[4096];
    const int t = threadIdx.x;
    const int lane = t & 63;
    const int w = t >> 6;
    const int wr = w >> 1, wc = w & 1;
    const int row0 = blockIdx.y * 128;
    const int col0 = blockIdx.x * 128;
    const int Kt = K0 + K1;
    const int fm = lane & 15;   // m (or n) within 16x16 fragment
    const int fq = lane >> 4;   // k-chunk: k = fq*8 + j

    f32x4 acc[4][4] = {};

    for (int kb = 0; kb < Kt; kb += 32) {
        const bf16* Ap; int sK, kr;
        if (kb < K0) { Ap = A0; sK = K0; kr = kb; }
        else         { Ap = A1; sK = K1; kr = kb - K0; }
        int ka = kr + fq * 8;
        int kbt = kb + fq * 8;
        // wave w stages A frags {w, w+4} and B frags {w, w+4} (1KB each)
        glds16(Ap + (size_t)(row0 + w * 16 + fm) * sK + ka,        &sA[w * 512]);
        glds16(Ap + (size_t)(row0 + (w + 4) * 16 + fm) * sK + ka,  &sA[(w + 4) * 512]);
        glds16(Bt + (size_t)(col0 + w * 16 + fm) * Kt + kbt,       &sB[w * 512]);
        glds16(Bt + (size_t)(col0 + (w + 4) * 16 + fm) * Kt + kbt, &sB[(w + 4) * 512]);
        __syncthreads();
        bf16x8 af[4], bfr[4];
#pragma unroll
        for (int i = 0; i < 4; i++) {
            af[i]  = *(const bf16x8*)&sA[(wr * 4 + i) * 512 + lane * 8];
            bfr[i] = *(const bf16x8*)&sB[(wc * 4 + i) * 512 + lane * 8];
        }
#pragma unroll
        for (int i = 0; i < 4; i++)
#pragma unroll
            for (int j = 0; j < 4; j++)
                acc[i][j] = __builtin_amdgcn_mfma_f32_16x16x32_bf16(af[i], bfr[j], acc[i][j], 0, 0, 0);
        __syncthreads();
    }
#pragma unroll
    for (int j = 0; j < 4; j++) {
        int col = col0 + wc * 64 + j * 16 + fm;
        float bs = bias[col];
#pragma unroll
        for (int i = 0; i < 4; i++) {
#pragma unroll
            for (int v = 0; v < 4; v++) {
                int row = row0 + wr * 64 + i * 16 + fq * 4 + v;
                float xv = acc[i][j][v] + bs;
                if (relu) xv = fmaxf(xv, 0.f);
                out[(size_t)row * N + col] = (bf16)xv;
            }
        }
    }
}

// ---------- row L2-normalize (pre-relu norm) then ReLU, bf16 in place ------
__global__ __launch_bounds__(256) void norm_relu_b(bf16x8* __restrict__ h, int F8) {
    int wid = threadIdx.x >> 6, lane = threadIdx.x & 63;
    size_t row = (size_t)blockIdx.x * 4 + wid;
    bf16x8* p = h + row * F8;
    float ss = 0.f;
    for (int j = lane; j < F8; j += 64) {
        bf16x8 v = p[j];
#pragma unroll
        for (int c = 0; c < 8; c++) { float f = (float)v[c]; ss += f * f; }
    }
    ss += __shfl_xor(ss, 32); ss += __shfl_xor(ss, 16); ss += __shfl_xor(ss, 8);
    ss += __shfl_xor(ss, 4);  ss += __shfl_xor(ss, 2);  ss += __shfl_xor(ss, 1);
    float inv = 1.f / fmaxf(sqrtf(ss), 1e-12f);
    for (int j = lane; j < F8; j += 64) {
        bf16x8 v = p[j], o;
#pragma unroll
        for (int c = 0; c < 8; c++) o[c] = (bf16)fmaxf((float)v[c] * inv, 0.f);
        p[j] = o;
    }
}

// ---------- final FC (1024 -> 10) + softmax; one wave per batch element ----
__global__ __launch_bounds__(256) void fc_softmax(const bf16x8* __restrict__ h,
                                                  const float* __restrict__ Wfc,
                                                  const float* __restrict__ bfc,
                                                  float* __restrict__ outp) {
    __shared__ float WT[10][1024];
    int t = threadIdx.x;
    for (int i = t; i < 10240; i += 256) { int o = i % 10, k = i / 10; WT[o][k] = Wfc[i]; }
    __syncthreads();
    int wid = t >> 6, lane = t & 63;
    size_t e = (size_t)blockIdx.x * 4 + wid;
    const bf16x8* hp = h + e * 128;
    float acc[10];
#pragma unroll
    for (int o = 0; o < 10; o++) acc[o] = 0.f;
#pragma unroll
    for (int j = 0; j < 2; j++) {
        int ch = j * 64 + lane;
        bf16x8 v = hp[ch];
        float f[8];
#pragma unroll
        for (int c = 0; c < 8; c++) f[c] = (float)v[c];
        int k0 = ch * 8;
#pragma unroll
        for (int o = 0; o < 10; o++) {
            const float* wr = &WT[o][k0];
            float s = 0.f;
#pragma unroll
            for (int c = 0; c < 8; c++) s += f[c] * wr[c];
            acc[o] += s;
        }
    }
#pragma unroll
    for (int o = 0; o < 10; o++) {
        float v = acc[o];
        v += __shfl_xor(v, 32); v += __shfl_xor(v, 16); v += __shfl_xor(v, 8);
        v += __shfl_xor(v, 4);  v += __shfl_xor(v, 2);  v += __shfl_xor(v, 1);
        acc[o] = v + bfc[o];
    }
    float mx = acc[0];
#pragma unroll
    for (int o = 1; o < 10; o++) mx = fmaxf(mx, acc[o]);
    float sum = 0.f, p[10];
#pragma unroll
    for (int o = 0; o < 10; o++) { p[o] = expf(acc[o] - mx); sum += p[o]; }
    float inv = 1.f / sum;
    if (lane < 10) outp[e * 10 + lane] = p[lane] * inv;
}

// ---------------------------------------------------------------------------
extern "C" void kernel_launch(void* const* d_in, const int* in_sizes, int n_in,
                              void* d_out, int out_size, void* d_ws, size_t ws_size,
                              hipStream_t stream) {
    const float* x   = (const float*)d_in[0];
    const int*   ei  = (const int*)d_in[1];
    const float* W1  = (const float*)d_in[2];
    const float* b1  = (const float*)d_in[3];
    const float* Wl2 = (const float*)d_in[4];
    const float* bl2 = (const float*)d_in[5];
    const float* Wr2 = (const float*)d_in[6];
    const float* Wl3 = (const float*)d_in[7];
    const float* bl3 = (const float*)d_in[8];
    const float* Wr3 = (const float*)d_in[9];
    const float* Wl4 = (const float*)d_in[10];
    const float* bl4 = (const float*)d_in[11];
    const float* Wr4 = (const float*)d_in[12];
    const float* Wfc = (const float*)d_in[13];
    const float* bfc = (const float*)d_in[14];
    float* out = (float*)d_out;

    const int B = 32768;
    char* base = (char*)d_ws;
    float* gmat = (float*)base;
    bf16* Wt1 = (bf16*)(base + 4096);                  // [1024 x 64]
    bf16* Wt2 = Wt1 + 1024 * 64;                       // [512 x 2048]
    bf16* Wt3 = Wt2 + 512 * 2048;                      // [256 x 1024]
    bf16* Wt4 = Wt3 + 256 * 1024;                      // [256 x 512]
    char* sl  = (char*)(Wt4 + 256 * 512);
    size_t fixed = (size_t)(sl - base);

    // per-element bf16 elems: 256+4096+4096+2048+2048+1024+1024+1024 = 15616
    // -> 31232 bytes per batch element
    int Bs = B;
    while (Bs > 512 && fixed + (size_t)Bs * 31232 > ws_size) Bs >>= 1;
    int nslice = B / Bs;
    int M = Bs * 4;

    bf16* xb   = (bf16*)sl;
    bf16* h1b  = xb   + (size_t)Bs * 256;
    bf16* agg1 = h1b  + (size_t)Bs * 4096;
    bf16* h2b  = agg1 + (size_t)Bs * 4096;
    bf16* agg2 = h2b  + (size_t)Bs * 2048;
    bf16* h3b  = agg2 + (size_t)Bs * 2048;
    bf16* agg3 = h3b  + (size_t)Bs * 1024;
    bf16* h4b  = agg3 + (size_t)Bs * 1024;

    hipLaunchKernelGGL(k_setup, dim3(1), dim3(64), 0, stream, ei, gmat);
    hipLaunchKernelGGL(wtrans, dim3((1024 * 64 + 255) / 256), dim3(256), 0, stream,
                       W1, 64, (const float*)nullptr, 0, 1024, Wt1);
    hipLaunchKernelGGL(wtrans, dim3((512 * 2048 + 255) / 256), dim3(256), 0, stream,
                       Wl2, 1024, Wr2, 1024, 512, Wt2);
    hipLaunchKernelGGL(wtrans, dim3((256 * 1024 + 255) / 256), dim3(256), 0, stream,
                       Wl3, 512, Wr3, 512, 256, Wt3);
    hipLaunchKernelGGL(wtrans, dim3((256 * 512 + 255) / 256), dim3(256), 0, stream,
                       Wl4, 256, Wr4, 256, 256, Wt4);

    for (int s = 0; s < nslice; s++) {
        const float* xs = x + (size_t)s * Bs * 256;
        // L1: GCN aggregate-first, then MFMA GEMM 64->1024 (+bias+ReLU)
        hipLaunchKernelGGL(agg_x, dim3(Bs / 8), dim3(256), 0, stream,
                           (const float4*)xs, (bf16x8*)xb, gmat);
        hipLaunchKernelGGL(gemm_mfma, dim3(8, M / 128), dim3(256), 0, stream,
                           xb, 64, (const bf16*)nullptr, 0, Wt1, b1, h1b, 1024, 1);
        // L2: SAGE 1024->512   (h1b feats=1024 -> K8=128, grid M*K8/256 = Bs*2)
        hipLaunchKernelGGL(agg_b, dim3(Bs * 2), dim3(256), 0, stream,
                           (const bf16x8*)h1b, (bf16x8*)agg1, gmat + 16, 128);
        hipLaunchKernelGGL(gemm_mfma, dim3(4, M / 128), dim3(256), 0, stream,
                           agg1, 1024, h1b, 1024, Wt2, bl2, h2b, 512, 0);
        hipLaunchKernelGGL(norm_relu_b, dim3(Bs), dim3(256), 0, stream, (bf16x8*)h2b, 64);
        // L3: SAGE 512->256    (h2b feats=512 -> K8=64, grid Bs)
        hipLaunchKernelGGL(agg_b, dim3(Bs), dim3(256), 0, stream,
                           (const bf16x8*)h2b, (bf16x8*)agg2, gmat + 16, 64);
        hipLaunchKernelGGL(gemm_mfma, dim3(2, M / 128), dim3(256), 0, stream,
                           agg2, 512, h2b, 512, Wt3, bl3, h3b, 256, 0);
        hipLaunchKernelGGL(norm_relu_b, dim3(Bs), dim3(256), 0, stream, (bf16x8*)h3b, 32);
        // L4: SAGE 256->256    (h3b feats=256 -> K8=32, grid Bs/2)
        hipLaunchKernelGGL(agg_b, dim3(Bs / 2), dim3(256), 0, stream,
                           (const bf16x8*)h3b, (bf16x8*)agg3, gmat + 16, 32);
        hipLaunchKernelGGL(gemm_mfma, dim3(2, M / 128), dim3(256), 0, stream,
                           agg3, 256, h3b, 256, Wt4, bl4, h4b, 256, 0);
        hipLaunchKernelGGL(norm_relu_b, dim3(Bs), dim3(256), 0, stream, (bf16x8*)h4b, 32);
        // FC + softmax (fp32 internals, bf16 input)
        hipLaunchKernelGGL(fc_softmax, dim3(Bs / 4), dim3(256), 0, stream,
                           (const bf16x8*)h4b, Wfc, bfc, out + (size_t)s * Bs * 10);
    }
}

// Round 4
// 1322.573 us; speedup vs baseline: 5.3488x; 1.1367x over previous
//
#include <hip/hip_runtime.h>
#include <stdint.h>
#include <math.h>

typedef __bf16 bf16;
typedef __attribute__((ext_vector_type(8))) __bf16 bf16x8;
typedef __attribute__((ext_vector_type(4))) float f32x4;

#define AS1 __attribute__((address_space(1)))
#define AS3 __attribute__((address_space(3)))

__device__ __forceinline__ void glds16(const void* g, void* l) {
    __builtin_amdgcn_global_load_lds((const AS1 uint32_t*)g, (AS3 uint32_t*)l, 16, 0, 0);
}

// ---------- setup: A_gcn (gmat[0..15]) and M_sage (gmat[16..31]) -----------
__global__ void k_setup(const int* __restrict__ ei, float* __restrict__ gmat) {
    if (threadIdx.x != 0 || blockIdx.x != 0) return;
    bool is64 = true;
    for (int i = 0; i < 12; i++) if (ei[2 * i + 1] != 0) { is64 = false; break; }
    int src[12], dst[12];
    for (int e = 0; e < 12; e++) {
        if (is64) { src[e] = ei[2 * e]; dst[e] = ei[24 + 2 * e]; }
        else      { src[e] = ei[e];     dst[e] = ei[12 + e]; }
    }
    float deg[4] = {1.f, 1.f, 1.f, 1.f};
    for (int e = 0; e < 12; e++) deg[dst[e]] += 1.f;
    float dinv[4];
    for (int n = 0; n < 4; n++) dinv[n] = 1.f / sqrtf(deg[n]);
    float A[16];
    for (int i = 0; i < 16; i++) A[i] = 0.f;
    for (int e = 0; e < 12; e++) A[dst[e] * 4 + src[e]] += dinv[src[e]] * dinv[dst[e]];
    for (int n = 0; n < 4; n++) A[n * 4 + n] += dinv[n] * dinv[n];
    float cnt[4] = {0.f, 0.f, 0.f, 0.f};
    for (int e = 0; e < 12; e++) cnt[dst[e]] += 1.f;
    for (int n = 0; n < 4; n++) cnt[n] = fmaxf(cnt[n], 1.f);
    float Mm[16];
    for (int i = 0; i < 16; i++) Mm[i] = 0.f;
    for (int e = 0; e < 12; e++) Mm[dst[e] * 4 + src[e]] += 1.f;
    for (int n = 0; n < 4; n++)
        for (int m = 0; m < 4; m++) Mm[n * 4 + m] /= cnt[n];
    for (int i = 0; i < 16; i++) { gmat[i] = A[i]; gmat[16 + i] = Mm[i]; }
}

// ---------- Wt1: transpose W [K,N] -> Bt [N,K] bf16 ------------------------
__global__ __launch_bounds__(256) void wtrans(const float* __restrict__ W, int K,
                                              int N, bf16* __restrict__ Wt) {
    int idx = blockIdx.x * 256 + threadIdx.x;
    if (idx >= N * K) return;
    int n = idx / K, k = idx - n * K;
    Wt[idx] = (bf16)W[(size_t)k * N + n];
}

// ---------- stacked-N transpose: Bt[N=2F, K]; n<F -> Wl, else Wr -----------
__global__ __launch_bounds__(256) void wtransN(const float* __restrict__ Wl,
                                               const float* __restrict__ Wr,
                                               int K, int F, bf16* __restrict__ Bt) {
    int idx = blockIdx.x * 256 + threadIdx.x;
    if (idx >= 2 * F * K) return;
    int n = idx / K, k = idx - n * K;
    float v = (n < F) ? Wl[(size_t)k * F + n] : Wr[(size_t)k * F + (n - F)];
    Bt[idx] = (bf16)v;
}

// ---------- GCN aggregate on fp32 x -> bf16 [M,64] -------------------------
__global__ __launch_bounds__(256) void agg_x(const float4* __restrict__ x,
                                             bf16x8* __restrict__ out,
                                             const float* __restrict__ gm) {
    int i = blockIdx.x * 256 + threadIdx.x;   // over M*8 chunks (K=64 -> 8 chunks)
    int kv = i & 7; int rn = i >> 3; int n = rn & 3;
    const float4* base = x + (size_t)(rn & ~3) * 16 + kv * 2;
    float w[4] = {gm[n * 4], gm[n * 4 + 1], gm[n * 4 + 2], gm[n * 4 + 3]};
    float4 va[4][2];
#pragma unroll
    for (int m = 0; m < 4; m++) { va[m][0] = base[m * 16]; va[m][1] = base[m * 16 + 1]; }
    bf16x8 o;
#pragma unroll
    for (int c = 0; c < 8; c++) {
        int h = c >> 2, cc = c & 3;
        float s = 0.f;
#pragma unroll
        for (int m = 0; m < 4; m++) s += w[m] * ((const float*)&va[m][h])[cc];
        o[c] = (bf16)s;
    }
    out[i] = o;
}

// ---------- MFMA GEMM: out[M,N] = A @ Bt^T (+bias)(+relu), bf16 ------------
// Bt is [N,K] row-major. 128x128 tile, BK=32, fragment-ordered LDS (0 conflicts).
__global__ __launch_bounds__(256, 4) void gemm_mfma(
    const bf16* __restrict__ A, int K,
    const bf16* __restrict__ Bt,
    const float* __restrict__ bias,
    bf16* __restrict__ out, int N, int relu) {
    __shared__ bf16 sA[4096];   // 8 frags x 512 elems (16 rows x 32 k)
    __shared__ bf16 sB[4096];
    const int t = threadIdx.x;
    const int lane = t & 63;
    const int w = t >> 6;
    const int wr = w >> 1, wc = w & 1;
    const int row0 = blockIdx.y * 128;
    const int col0 = blockIdx.x * 128;
    const int fm = lane & 15;   // m (or n) within 16x16 fragment
    const int fq = lane >> 4;   // k-chunk: k = fq*8 + j

    f32x4 acc[4][4] = {};

    for (int kb = 0; kb < K; kb += 32) {
        int ka = kb + fq * 8;
        glds16(A  + (size_t)(row0 + w * 16 + fm) * K + ka,       &sA[w * 512]);
        glds16(A  + (size_t)(row0 + (w + 4) * 16 + fm) * K + ka, &sA[(w + 4) * 512]);
        glds16(Bt + (size_t)(col0 + w * 16 + fm) * K + ka,       &sB[w * 512]);
        glds16(Bt + (size_t)(col0 + (w + 4) * 16 + fm) * K + ka, &sB[(w + 4) * 512]);
        __syncthreads();
        bf16x8 af[4], bfr[4];
#pragma unroll
        for (int i = 0; i < 4; i++) {
            af[i]  = *(const bf16x8*)&sA[(wr * 4 + i) * 512 + lane * 8];
            bfr[i] = *(const bf16x8*)&sB[(wc * 4 + i) * 512 + lane * 8];
        }
#pragma unroll
        for (int i = 0; i < 4; i++)
#pragma unroll
            for (int j = 0; j < 4; j++)
                acc[i][j] = __builtin_amdgcn_mfma_f32_16x16x32_bf16(af[i], bfr[j], acc[i][j], 0, 0, 0);
        __syncthreads();
    }
#pragma unroll
    for (int j = 0; j < 4; j++) {
        int col = col0 + wc * 64 + j * 16 + fm;
        float bs = bias ? bias[col] : 0.f;
#pragma unroll
        for (int i = 0; i < 4; i++) {
#pragma unroll
            for (int v = 0; v < 4; v++) {
                int row = row0 + wr * 64 + i * 16 + fq * 4 + v;
                float xv = acc[i][j][v] + bs;
                if (relu) xv = fmaxf(xv, 0.f);
                out[(size_t)row * N + col] = (bf16)xv;
            }
        }
    }
}

// ---------- SAGE epilogue: node-mix + bias + L2-norm + ReLU ----------------
// G [M, 2F]: left half = h@Wl, right half = h@Wr. One block = one 4-node
// group; wave wid handles output row (grp*4 + wid). F8 = F/8 <= 64.
__global__ __launch_bounds__(256) void mix_norm(const bf16x8* __restrict__ G,
                                                bf16x8* __restrict__ out,
                                                const float* __restrict__ gm,
                                                const float* __restrict__ bias,
                                                int F8) {
    int wid = threadIdx.x >> 6, lane = threadIdx.x & 63;
    size_t base = (size_t)blockIdx.x * 4;
    int n = wid;
    float w0 = gm[n * 4], w1 = gm[n * 4 + 1], w2 = gm[n * 4 + 2], w3 = gm[n * 4 + 3];
    size_t rs = 2 * (size_t)F8;   // G row stride in chunks
    float vals[8];
    float ss = 0.f;
    if (lane < F8) {
        bf16x8 l0 = G[(base + 0) * rs + lane];
        bf16x8 l1 = G[(base + 1) * rs + lane];
        bf16x8 l2 = G[(base + 2) * rs + lane];
        bf16x8 l3 = G[(base + 3) * rs + lane];
        bf16x8 r  = G[(base + n) * rs + F8 + lane];
        const float4* b4 = (const float4*)bias;
        float4 ba = b4[lane * 2], bb = b4[lane * 2 + 1];
        const float* bp = (const float*)&ba;
#pragma unroll
        for (int c = 0; c < 8; c++) {
            float bsv = (c < 4) ? bp[c] : ((const float*)&bb)[c - 4];
            float v = w0 * (float)l0[c] + w1 * (float)l1[c] +
                      w2 * (float)l2[c] + w3 * (float)l3[c] + (float)r[c] + bsv;
            vals[c] = v; ss += v * v;
        }
    }
    ss += __shfl_xor(ss, 32); ss += __shfl_xor(ss, 16); ss += __shfl_xor(ss, 8);
    ss += __shfl_xor(ss, 4);  ss += __shfl_xor(ss, 2);  ss += __shfl_xor(ss, 1);
    float inv = 1.f / fmaxf(sqrtf(ss), 1e-12f);
    if (lane < F8) {
        bf16x8 o;
#pragma unroll
        for (int c = 0; c < 8; c++) o[c] = (bf16)fmaxf(vals[c] * inv, 0.f);
        out[(base + n) * F8 + lane] = o;
    }
}

// ---------- final FC (1024 -> 10) + softmax; one wave per batch element ----
__global__ __launch_bounds__(256) void fc_softmax(const bf16x8* __restrict__ h,
                                                  const float* __restrict__ Wfc,
                                                  const float* __restrict__ bfc,
                                                  float* __restrict__ outp) {
    __shared__ float WT[10][1024];
    int t = threadIdx.x;
    for (int i = t; i < 10240; i += 256) { int o = i % 10, k = i / 10; WT[o][k] = Wfc[i]; }
    __syncthreads();
    int wid = t >> 6, lane = t & 63;
    size_t e = (size_t)blockIdx.x * 4 + wid;
    const bf16x8* hp = h + e * 128;
    float acc[10];
#pragma unroll
    for (int o = 0; o < 10; o++) acc[o] = 0.f;
#pragma unroll
    for (int j = 0; j < 2; j++) {
        int ch = j * 64 + lane;
        bf16x8 v = hp[ch];
        float f[8];
#pragma unroll
        for (int c = 0; c < 8; c++) f[c] = (float)v[c];
        int k0 = ch * 8;
#pragma unroll
        for (int o = 0; o < 10; o++) {
            const float* wr = &WT[o][k0];
            float s = 0.f;
#pragma unroll
            for (int c = 0; c < 8; c++) s += f[c] * wr[c];
            acc[o] += s;
        }
    }
#pragma unroll
    for (int o = 0; o < 10; o++) {
        float v = acc[o];
        v += __shfl_xor(v, 32); v += __shfl_xor(v, 16); v += __shfl_xor(v, 8);
        v += __shfl_xor(v, 4);  v += __shfl_xor(v, 2);  v += __shfl_xor(v, 1);
        acc[o] = v + bfc[o];
    }
    float mx = acc[0];
#pragma unroll
    for (int o = 1; o < 10; o++) mx = fmaxf(mx, acc[o]);
    float sum = 0.f, p[10];
#pragma unroll
    for (int o = 0; o < 10; o++) { p[o] = expf(acc[o] - mx); sum += p[o]; }
    float inv = 1.f / sum;
    if (lane < 10) outp[e * 10 + lane] = p[lane] * inv;
}

// ---------------------------------------------------------------------------
extern "C" void kernel_launch(void* const* d_in, const int* in_sizes, int n_in,
                              void* d_out, int out_size, void* d_ws, size_t ws_size,
                              hipStream_t stream) {
    const float* x   = (const float*)d_in[0];
    const int*   ei  = (const int*)d_in[1];
    const float* W1  = (const float*)d_in[2];
    const float* b1  = (const float*)d_in[3];
    const float* Wl2 = (const float*)d_in[4];
    const float* bl2 = (const float*)d_in[5];
    const float* Wr2 = (const float*)d_in[6];
    const float* Wl3 = (const float*)d_in[7];
    const float* bl3 = (const float*)d_in[8];
    const float* Wr3 = (const float*)d_in[9];
    const float* Wl4 = (const float*)d_in[10];
    const float* bl4 = (const float*)d_in[11];
    const float* Wr4 = (const float*)d_in[12];
    const float* Wfc = (const float*)d_in[13];
    const float* bfc = (const float*)d_in[14];
    float* out = (float*)d_out;

    const int B = 32768;
    char* base = (char*)d_ws;
    float* gmat = (float*)base;
    bf16* Wt1 = (bf16*)(base + 4096);                  // [1024 x 64]
    bf16* Wt2 = Wt1 + 1024 * 64;                       // [1024 x 1024] (N-stacked Wl2|Wr2)
    bf16* Wt3 = Wt2 + 1024 * 1024;                     // [512 x 512]
    bf16* Wt4 = Wt3 + 512 * 512;                       // [512 x 256]
    char* sl  = (char*)(Wt4 + 512 * 256);
    size_t fixed = (size_t)(sl - base);

    // per-elem bf16: R0 256 + R1 4096 + R2 4096 + R3 2048 + R4 2048 = 12544 -> 25088 B
    int Bs = B;
    while (Bs > 512 && fixed + (size_t)Bs * 25088 > ws_size) Bs >>= 1;
    int nslice = B / Bs;
    int M = Bs * 4;

    bf16* R0 = (bf16*)sl;                       // xb  [M,64]
    bf16* R1 = R0 + (size_t)Bs * 256;           // h1b [M,1024] ; later G3 [M,512]
    bf16* R2 = R1 + (size_t)Bs * 4096;          // G2  [M,1024] ; later G4 [M,512]
    bf16* R3 = R2 + (size_t)Bs * 4096;          // h2b [M,512]  ; later h4b [M,256]
    bf16* R4 = R3 + (size_t)Bs * 2048;          // h3b [M,256]

    hipLaunchKernelGGL(k_setup, dim3(1), dim3(64), 0, stream, ei, gmat);
    hipLaunchKernelGGL(wtrans, dim3((1024 * 64 + 255) / 256), dim3(256), 0, stream,
                       W1, 64, 1024, Wt1);
    hipLaunchKernelGGL(wtransN, dim3((1024 * 1024 + 255) / 256), dim3(256), 0, stream,
                       Wl2, Wr2, 1024, 512, Wt2);
    hipLaunchKernelGGL(wtransN, dim3((512 * 512 + 255) / 256), dim3(256), 0, stream,
                       Wl3, Wr3, 512, 256, Wt3);
    hipLaunchKernelGGL(wtransN, dim3((512 * 256 + 255) / 256), dim3(256), 0, stream,
                       Wl4, Wr4, 256, 256, Wt4);

    for (int s = 0; s < nslice; s++) {
        const float* xs = x + (size_t)s * Bs * 256;
        // L1: GCN aggregate-first, then GEMM 64->1024 (+bias+ReLU)
        hipLaunchKernelGGL(agg_x, dim3(Bs / 8), dim3(256), 0, stream,
                           (const float4*)xs, (bf16x8*)R0, gmat);
        hipLaunchKernelGGL(gemm_mfma, dim3(8, M / 128), dim3(256), 0, stream,
                           R0, 64, Wt1, b1, R1, 1024, 1);
        // L2: G2 = h1 @ [Wl2|Wr2]  (N=1024, K=1024), then mix+norm -> h2 (F=512)
        hipLaunchKernelGGL(gemm_mfma, dim3(8, M / 128), dim3(256), 0, stream,
                           R1, 1024, Wt2, (const float*)nullptr, R2, 1024, 0);
        hipLaunchKernelGGL(mix_norm, dim3(Bs), dim3(256), 0, stream,
                           (const bf16x8*)R2, (bf16x8*)R3, gmat + 16, bl2, 64);
        // L3: G3 = h2 @ [Wl3|Wr3]  (N=512, K=512) -> h3 (F=256)
        hipLaunchKernelGGL(gemm_mfma, dim3(4, M / 128), dim3(256), 0, stream,
                           R3, 512, Wt3, (const float*)nullptr, R1, 512, 0);
        hipLaunchKernelGGL(mix_norm, dim3(Bs), dim3(256), 0, stream,
                           (const bf16x8*)R1, (bf16x8*)R4, gmat + 16, bl3, 32);
        // L4: G4 = h3 @ [Wl4|Wr4]  (N=512, K=256) -> h4 (F=256)
        hipLaunchKernelGGL(gemm_mfma, dim3(4, M / 128), dim3(256), 0, stream,
                           R4, 256, Wt4, (const float*)nullptr, R2, 512, 0);
        hipLaunchKernelGGL(mix_norm, dim3(Bs), dim3(256), 0, stream,
                           (const bf16x8*)R2, (bf16x8*)R3, gmat + 16, bl4, 32);
        // FC + softmax (reads h4b in R3)
        hipLaunchKernelGGL(fc_softmax, dim3(Bs / 4), dim3(256), 0, stream,
                           (const bf16x8*)R3, Wfc, bfc, out + (size_t)s * Bs * 10);
    }
}

// Round 5
// 1280.205 us; speedup vs baseline: 5.5258x; 1.0331x over previous
//
#include <hip/hip_runtime.h>
#include <stdint.h>
#include <math.h>

typedef __bf16 bf16;
typedef __attribute__((ext_vector_type(8))) __bf16 bf16x8;
typedef __attribute__((ext_vector_type(4))) float f32x4;

#define AS1 __attribute__((address_space(1)))
#define AS3 __attribute__((address_space(3)))

__device__ __forceinline__ void glds16(const void* g, void* l) {
    __builtin_amdgcn_global_load_lds((const AS1 uint32_t*)g, (AS3 uint32_t*)l, 16, 0, 0);
}

// ---------- setup: A_gcn (gmat[0..15]) and M_sage (gmat[16..31]) -----------
__global__ void k_setup(const int* __restrict__ ei, float* __restrict__ gmat) {
    if (threadIdx.x != 0 || blockIdx.x != 0) return;
    bool is64 = true;
    for (int i = 0; i < 12; i++) if (ei[2 * i + 1] != 0) { is64 = false; break; }
    int src[12], dst[12];
    for (int e = 0; e < 12; e++) {
        if (is64) { src[e] = ei[2 * e]; dst[e] = ei[24 + 2 * e]; }
        else      { src[e] = ei[e];     dst[e] = ei[12 + e]; }
    }
    float deg[4] = {1.f, 1.f, 1.f, 1.f};
    for (int e = 0; e < 12; e++) deg[dst[e]] += 1.f;
    float dinv[4];
    for (int n = 0; n < 4; n++) dinv[n] = 1.f / sqrtf(deg[n]);
    float A[16];
    for (int i = 0; i < 16; i++) A[i] = 0.f;
    for (int e = 0; e < 12; e++) A[dst[e] * 4 + src[e]] += dinv[src[e]] * dinv[dst[e]];
    for (int n = 0; n < 4; n++) A[n * 4 + n] += dinv[n] * dinv[n];
    float cnt[4] = {0.f, 0.f, 0.f, 0.f};
    for (int e = 0; e < 12; e++) cnt[dst[e]] += 1.f;
    for (int n = 0; n < 4; n++) cnt[n] = fmaxf(cnt[n], 1.f);
    float Mm[16];
    for (int i = 0; i < 16; i++) Mm[i] = 0.f;
    for (int e = 0; e < 12; e++) Mm[dst[e] * 4 + src[e]] += 1.f;
    for (int n = 0; n < 4; n++)
        for (int m = 0; m < 4; m++) Mm[n * 4 + m] /= cnt[n];
    for (int i = 0; i < 16; i++) { gmat[i] = A[i]; gmat[16 + i] = Mm[i]; }
}

// ---------- Wt1: transpose W [K,N] -> Bt [N,K] bf16 ------------------------
__global__ __launch_bounds__(256) void wtrans(const float* __restrict__ W, int K,
                                              int N, bf16* __restrict__ Wt) {
    int idx = blockIdx.x * 256 + threadIdx.x;
    if (idx >= N * K) return;
    int n = idx / K, k = idx - n * K;
    Wt[idx] = (bf16)W[(size_t)k * N + n];
}

// ---------- stacked-N transpose: Bt[N=2F, K]; n<F -> Wl, else Wr -----------
__global__ __launch_bounds__(256) void wtransN(const float* __restrict__ Wl,
                                               const float* __restrict__ Wr,
                                               int K, int F, bf16* __restrict__ Bt) {
    int idx = blockIdx.x * 256 + threadIdx.x;
    if (idx >= 2 * F * K) return;
    int n = idx / K, k = idx - n * K;
    float v = (n < F) ? Wl[(size_t)k * F + n] : Wr[(size_t)k * F + (n - F)];
    Bt[idx] = (bf16)v;
}

// ---------- GCN aggregate on fp32 x -> bf16 [M,64] -------------------------
__global__ __launch_bounds__(256) void agg_x(const float4* __restrict__ x,
                                             bf16x8* __restrict__ out,
                                             const float* __restrict__ gm) {
    int i = blockIdx.x * 256 + threadIdx.x;   // over M*8 chunks (K=64 -> 8 chunks)
    int kv = i & 7; int rn = i >> 3; int n = rn & 3;
    const float4* base = x + (size_t)(rn & ~3) * 16 + kv * 2;
    float w[4] = {gm[n * 4], gm[n * 4 + 1], gm[n * 4 + 2], gm[n * 4 + 3]};
    float4 va[4][2];
#pragma unroll
    for (int m = 0; m < 4; m++) { va[m][0] = base[m * 16]; va[m][1] = base[m * 16 + 1]; }
    bf16x8 o;
#pragma unroll
    for (int c = 0; c < 8; c++) {
        int h = c >> 2, cc = c & 3;
        float s = 0.f;
#pragma unroll
        for (int m = 0; m < 4; m++) s += w[m] * ((const float*)&va[m][h])[cc];
        o[c] = (bf16)s;
    }
    out[i] = o;
}

// ---------- MFMA GEMM: out[M,N] = A @ Bt^T (+bias)(+relu), bf16 ------------
// Bt is [N,K] row-major. 128x128 tile, BK=64 (32 MFMAs/wave per barrier),
// fragment-ordered LDS (0 conflicts). Requires K % 64 == 0.
__global__ __launch_bounds__(256, 4) void gemm_mfma(
    const bf16* __restrict__ A, int K,
    const bf16* __restrict__ Bt,
    const float* __restrict__ bias,
    bf16* __restrict__ out, int N, int relu) {
    __shared__ bf16 sA[8192];   // 16 frags x 512 elems (16 rows x 32 k each)
    __shared__ bf16 sB[8192];
    const int t = threadIdx.x;
    const int lane = t & 63;
    const int w = t >> 6;
    const int wr = w >> 1, wc = w & 1;
    const int row0 = blockIdx.y * 128;
    const int col0 = blockIdx.x * 128;
    const int fm = lane & 15;   // m (or n) within 16x16 fragment
    const int fq = lane >> 4;   // k-chunk: k = fq*8 + j

    f32x4 acc[4][4] = {};

    const size_t rA0 = (size_t)(row0 + w * 16 + fm) * K;
    const size_t rA1 = (size_t)(row0 + (w + 4) * 16 + fm) * K;
    const size_t rB0 = (size_t)(col0 + w * 16 + fm) * K;
    const size_t rB1 = (size_t)(col0 + (w + 4) * 16 + fm) * K;

    for (int kb = 0; kb < K; kb += 64) {
        int ka = kb + fq * 8;
        // frag slot layout: (kHalf*8 + rowBlk) * 512
        glds16(A  + rA0 + ka,      &sA[w * 512]);
        glds16(A  + rA1 + ka,      &sA[(w + 4) * 512]);
        glds16(A  + rA0 + ka + 32, &sA[(8 + w) * 512]);
        glds16(A  + rA1 + ka + 32, &sA[(12 + w) * 512]);
        glds16(Bt + rB0 + ka,      &sB[w * 512]);
        glds16(Bt + rB1 + ka,      &sB[(w + 4) * 512]);
        glds16(Bt + rB0 + ka + 32, &sB[(8 + w) * 512]);
        glds16(Bt + rB1 + ka + 32, &sB[(12 + w) * 512]);
        __syncthreads();
#pragma unroll
        for (int h = 0; h < 2; h++) {
            bf16x8 af[4], bfr[4];
#pragma unroll
            for (int i = 0; i < 4; i++) {
                af[i]  = *(const bf16x8*)&sA[(h * 8 + wr * 4 + i) * 512 + lane * 8];
                bfr[i] = *(const bf16x8*)&sB[(h * 8 + wc * 4 + i) * 512 + lane * 8];
            }
#pragma unroll
            for (int i = 0; i < 4; i++)
#pragma unroll
                for (int j = 0; j < 4; j++)
                    acc[i][j] = __builtin_amdgcn_mfma_f32_16x16x32_bf16(af[i], bfr[j], acc[i][j], 0, 0, 0);
        }
        __syncthreads();
    }
#pragma unroll
    for (int j = 0; j < 4; j++) {
        int col = col0 + wc * 64 + j * 16 + fm;
        float bs = bias ? bias[col] : 0.f;
#pragma unroll
        for (int i = 0; i < 4; i++) {
#pragma unroll
            for (int v = 0; v < 4; v++) {
                int row = row0 + wr * 64 + i * 16 + fq * 4 + v;
                float xv = acc[i][j][v] + bs;
                if (relu) xv = fmaxf(xv, 0.f);
                out[(size_t)row * N + col] = (bf16)xv;
            }
        }
    }
}

// ---------- SAGE epilogue: node-mix + bias + L2-norm + ReLU ----------------
// G [M, 2F]: left half = h@Wl, right half = h@Wr. One block = one 4-node
// group; wave wid handles output row (grp*4 + wid). F8 = F/8 <= 64.
__global__ __launch_bounds__(256) void mix_norm(const bf16x8* __restrict__ G,
                                                bf16x8* __restrict__ out,
                                                const float* __restrict__ gm,
                                                const float* __restrict__ bias,
                                                int F8) {
    int wid = threadIdx.x >> 6, lane = threadIdx.x & 63;
    size_t base = (size_t)blockIdx.x * 4;
    int n = wid;
    float w0 = gm[n * 4], w1 = gm[n * 4 + 1], w2 = gm[n * 4 + 2], w3 = gm[n * 4 + 3];
    size_t rs = 2 * (size_t)F8;   // G row stride in chunks
    float vals[8];
    float ss = 0.f;
    if (lane < F8) {
        bf16x8 l0 = G[(base + 0) * rs + lane];
        bf16x8 l1 = G[(base + 1) * rs + lane];
        bf16x8 l2 = G[(base + 2) * rs + lane];
        bf16x8 l3 = G[(base + 3) * rs + lane];
        bf16x8 r  = G[(base + n) * rs + F8 + lane];
        const float4* b4 = (const float4*)bias;
        float4 ba = b4[lane * 2], bb = b4[lane * 2 + 1];
        const float* bp = (const float*)&ba;
#pragma unroll
        for (int c = 0; c < 8; c++) {
            float bsv = (c < 4) ? bp[c] : ((const float*)&bb)[c - 4];
            float v = w0 * (float)l0[c] + w1 * (float)l1[c] +
                      w2 * (float)l2[c] + w3 * (float)l3[c] + (float)r[c] + bsv;
            vals[c] = v; ss += v * v;
        }
    }
    ss += __shfl_xor(ss, 32); ss += __shfl_xor(ss, 16); ss += __shfl_xor(ss, 8);
    ss += __shfl_xor(ss, 4);  ss += __shfl_xor(ss, 2);  ss += __shfl_xor(ss, 1);
    float inv = 1.f / fmaxf(sqrtf(ss), 1e-12f);
    if (lane < F8) {
        bf16x8 o;
#pragma unroll
        for (int c = 0; c < 8; c++) o[c] = (bf16)fmaxf(vals[c] * inv, 0.f);
        out[(base + n) * F8 + lane] = o;
    }
}

// ---------- final FC (1024 -> 10) + softmax; one wave per batch element ----
__global__ __launch_bounds__(256) void fc_softmax(const bf16x8* __restrict__ h,
                                                  const float* __restrict__ Wfc,
                                                  const float* __restrict__ bfc,
                                                  float* __restrict__ outp) {
    __shared__ float WT[10][1024];
    int t = threadIdx.x;
    for (int i = t; i < 10240; i += 256) { int o = i % 10, k = i / 10; WT[o][k] = Wfc[i]; }
    __syncthreads();
    int wid = t >> 6, lane = t & 63;
    size_t e = (size_t)blockIdx.x * 4 + wid;
    const bf16x8* hp = h + e * 128;
    float acc[10];
#pragma unroll
    for (int o = 0; o < 10; o++) acc[o] = 0.f;
#pragma unroll
    for (int j = 0; j < 2; j++) {
        int ch = j * 64 + lane;
        bf16x8 v = hp[ch];
        float f[8];
#pragma unroll
        for (int c = 0; c < 8; c++) f[c] = (float)v[c];
        int k0 = ch * 8;
#pragma unroll
        for (int o = 0; o < 10; o++) {
            const float* wr = &WT[o][k0];
            float s = 0.f;
#pragma unroll
            for (int c = 0; c < 8; c++) s += f[c] * wr[c];
            acc[o] += s;
        }
    }
#pragma unroll
    for (int o = 0; o < 10; o++) {
        float v = acc[o];
        v += __shfl_xor(v, 32); v += __shfl_xor(v, 16); v += __shfl_xor(v, 8);
        v += __shfl_xor(v, 4);  v += __shfl_xor(v, 2);  v += __shfl_xor(v, 1);
        acc[o] = v + bfc[o];
    }
    float mx = acc[0];
#pragma unroll
    for (int o = 1; o < 10; o++) mx = fmaxf(mx, acc[o]);
    float sum = 0.f, p[10];
#pragma unroll
    for (int o = 0; o < 10; o++) { p[o] = expf(acc[o] - mx); sum += p[o]; }
    float inv = 1.f / sum;
    if (lane < 10) outp[e * 10 + lane] = p[lane] * inv;
}

// ---------------------------------------------------------------------------
extern "C" void kernel_launch(void* const* d_in, const int* in_sizes, int n_in,
                              void* d_out, int out_size, void* d_ws, size_t ws_size,
                              hipStream_t stream) {
    const float* x   = (const float*)d_in[0];
    const int*   ei  = (const int*)d_in[1];
    const float* W1  = (const float*)d_in[2];
    const float* b1  = (const float*)d_in[3];
    const float* Wl2 = (const float*)d_in[4];
    const float* bl2 = (const float*)d_in[5];
    const float* Wr2 = (const float*)d_in[6];
    const float* Wl3 = (const float*)d_in[7];
    const float* bl3 = (const float*)d_in[8];
    const float* Wr3 = (const float*)d_in[9];
    const float* Wl4 = (const float*)d_in[10];
    const float* bl4 = (const float*)d_in[11];
    const float* Wr4 = (const float*)d_in[12];
    const float* Wfc = (const float*)d_in[13];
    const float* bfc = (const float*)d_in[14];
    float* out = (float*)d_out;

    const int B = 32768;
    char* base = (char*)d_ws;
    float* gmat = (float*)base;
    bf16* Wt1 = (bf16*)(base + 4096);                  // [1024 x 64]
    bf16* Wt2 = Wt1 + 1024 * 64;                       // [1024 x 1024] (N-stacked Wl2|Wr2)
    bf16* Wt3 = Wt2 + 1024 * 1024;                     // [512 x 512]
    bf16* Wt4 = Wt3 + 512 * 512;                       // [512 x 256]
    char* sl  = (char*)(Wt4 + 512 * 256);
    size_t fixed = (size_t)(sl - base);

    // per-elem bf16 (aliased buffers): xb 256 + R1 4096 + R2 4096 = 8448 -> 16896 B
    int Bs = B;
    while (Bs > 512 && fixed + (size_t)Bs * 16896 > ws_size) Bs >>= 1;
    int nslice = B / Bs;
    int M = Bs * 4;

    bf16* R0 = (bf16*)sl;                       // xb  [M,64]
    bf16* R1 = R0 + (size_t)Bs * 256;           // h1 [M,1024]; then h2 [M,512]; h3/h4 [M,256]
    bf16* R2 = R1 + (size_t)Bs * 4096;          // G2 [M,1024]; then G3/G4 [M,512]

    hipLaunchKernelGGL(k_setup, dim3(1), dim3(64), 0, stream, ei, gmat);
    hipLaunchKernelGGL(wtrans, dim3((1024 * 64 + 255) / 256), dim3(256), 0, stream,
                       W1, 64, 1024, Wt1);
    hipLaunchKernelGGL(wtransN, dim3((1024 * 1024 + 255) / 256), dim3(256), 0, stream,
                       Wl2, Wr2, 1024, 512, Wt2);
    hipLaunchKernelGGL(wtransN, dim3((512 * 512 + 255) / 256), dim3(256), 0, stream,
                       Wl3, Wr3, 512, 256, Wt3);
    hipLaunchKernelGGL(wtransN, dim3((512 * 256 + 255) / 256), dim3(256), 0, stream,
                       Wl4, Wr4, 256, 256, Wt4);

    for (int s = 0; s < nslice; s++) {
        const float* xs = x + (size_t)s * Bs * 256;
        // L1: GCN aggregate-first, then GEMM 64->1024 (+bias+ReLU)
        hipLaunchKernelGGL(agg_x, dim3(Bs / 8), dim3(256), 0, stream,
                           (const float4*)xs, (bf16x8*)R0, gmat);
        hipLaunchKernelGGL(gemm_mfma, dim3(8, M / 128), dim3(256), 0, stream,
                           R0, 64, Wt1, b1, R1, 1024, 1);
        // L2: G2 = h1 @ [Wl2|Wr2]  (N=1024, K=1024); mix+norm -> h2 (F=512) into R1
        hipLaunchKernelGGL(gemm_mfma, dim3(8, M / 128), dim3(256), 0, stream,
                           R1, 1024, Wt2, (const float*)nullptr, R2, 1024, 0);
        hipLaunchKernelGGL(mix_norm, dim3(Bs), dim3(256), 0, stream,
                           (const bf16x8*)R2, (bf16x8*)R1, gmat + 16, bl2, 64);
        // L3: G3 = h2 @ [Wl3|Wr3]  (N=512, K=512) -> R2; mix -> h3 (F=256) into R1
        hipLaunchKernelGGL(gemm_mfma, dim3(4, M / 128), dim3(256), 0, stream,
                           R1, 512, Wt3, (const float*)nullptr, R2, 512, 0);
        hipLaunchKernelGGL(mix_norm, dim3(Bs), dim3(256), 0, stream,
                           (const bf16x8*)R2, (bf16x8*)R1, gmat + 16, bl3, 32);
        // L4: G4 = h3 @ [Wl4|Wr4]  (N=512, K=256) -> R2; mix -> h4 (F=256) into R1
        hipLaunchKernelGGL(gemm_mfma, dim3(4, M / 128), dim3(256), 0, stream,
                           R1, 256, Wt4, (const float*)nullptr, R2, 512, 0);
        hipLaunchKernelGGL(mix_norm, dim3(Bs), dim3(256), 0, stream,
                           (const bf16x8*)R2, (bf16x8*)R1, gmat + 16, bl4, 32);
        // FC + softmax (reads h4 in R1)
        hipLaunchKernelGGL(fc_softmax, dim3(Bs / 4), dim3(256), 0, stream,
                           (const bf16x8*)R1, Wfc, bfc, out + (size_t)s * Bs * 10);
    }
}

// Round 6
// 1214.869 us; speedup vs baseline: 5.8230x; 1.0538x over previous
//
#include <hip/hip_runtime.h>
#include <stdint.h>
#include <math.h>

typedef __bf16 bf16;
typedef __attribute__((ext_vector_type(8))) __bf16 bf16x8;
typedef __attribute__((ext_vector_type(4))) float f32x4;

#define AS1 __attribute__((address_space(1)))
#define AS3 __attribute__((address_space(3)))

__device__ __forceinline__ void glds16(const void* g, void* l) {
    __builtin_amdgcn_global_load_lds((const AS1 uint32_t*)g, (AS3 uint32_t*)l, 16, 0, 0);
}

// ---------- setup: A_gcn (gmat[0..15]) and M_sage (gmat[16..31]) -----------
__global__ void k_setup(const int* __restrict__ ei, float* __restrict__ gmat) {
    if (threadIdx.x != 0 || blockIdx.x != 0) return;
    bool is64 = true;
    for (int i = 0; i < 12; i++) if (ei[2 * i + 1] != 0) { is64 = false; break; }
    int src[12], dst[12];
    for (int e = 0; e < 12; e++) {
        if (is64) { src[e] = ei[2 * e]; dst[e] = ei[24 + 2 * e]; }
        else      { src[e] = ei[e];     dst[e] = ei[12 + e]; }
    }
    float deg[4] = {1.f, 1.f, 1.f, 1.f};
    for (int e = 0; e < 12; e++) deg[dst[e]] += 1.f;
    float dinv[4];
    for (int n = 0; n < 4; n++) dinv[n] = 1.f / sqrtf(deg[n]);
    float A[16];
    for (int i = 0; i < 16; i++) A[i] = 0.f;
    for (int e = 0; e < 12; e++) A[dst[e] * 4 + src[e]] += dinv[src[e]] * dinv[dst[e]];
    for (int n = 0; n < 4; n++) A[n * 4 + n] += dinv[n] * dinv[n];
    float cnt[4] = {0.f, 0.f, 0.f, 0.f};
    for (int e = 0; e < 12; e++) cnt[dst[e]] += 1.f;
    for (int n = 0; n < 4; n++) cnt[n] = fmaxf(cnt[n], 1.f);
    float Mm[16];
    for (int i = 0; i < 16; i++) Mm[i] = 0.f;
    for (int e = 0; e < 12; e++) Mm[dst[e] * 4 + src[e]] += 1.f;
    for (int n = 0; n < 4; n++)
        for (int m = 0; m < 4; m++) Mm[n * 4 + m] /= cnt[n];
    for (int i = 0; i < 16; i++) { gmat[i] = A[i]; gmat[16 + i] = Mm[i]; }
}

// ---------- Wt1: transpose W [K,N] -> Bt [N,K] bf16 ------------------------
__global__ __launch_bounds__(256) void wtrans(const float* __restrict__ W, int K,
                                              int N, bf16* __restrict__ Wt) {
    int idx = blockIdx.x * 256 + threadIdx.x;
    if (idx >= N * K) return;
    int n = idx / K, k = idx - n * K;
    Wt[idx] = (bf16)W[(size_t)k * N + n];
}

// ---------- interleaved stack: Bt[2F,K]; row 2f -> Wl col f, 2f+1 -> Wr ----
__global__ __launch_bounds__(256) void wtransI(const float* __restrict__ Wl,
                                               const float* __restrict__ Wr,
                                               int K, int F, bf16* __restrict__ Bt) {
    int idx = blockIdx.x * 256 + threadIdx.x;
    if (idx >= 2 * F * K) return;
    int n = idx / K, k = idx - n * K;
    int f = n >> 1;
    float v = (n & 1) ? Wr[(size_t)k * F + f] : Wl[(size_t)k * F + f];
    Bt[idx] = (bf16)v;
}

// ---------- cast fp32 x -> bf16 --------------------------------------------
__global__ __launch_bounds__(256) void cast_x(const float4* __restrict__ x,
                                              bf16x8* __restrict__ out) {
    int i = blockIdx.x * 256 + threadIdx.x;
    float4 a = x[2 * i], b = x[2 * i + 1];
    bf16x8 o;
    o[0] = (bf16)a.x; o[1] = (bf16)a.y; o[2] = (bf16)a.z; o[3] = (bf16)a.w;
    o[4] = (bf16)b.x; o[5] = (bf16)b.y; o[6] = (bf16)b.z; o[7] = (bf16)b.w;
    out[i] = o;
}

// ---------- zero ssq accumulators ------------------------------------------
__global__ __launch_bounds__(256) void k_zero(float4* __restrict__ p, int n4) {
    int i = blockIdx.x * 256 + threadIdx.x;
    if (i < n4) p[i] = make_float4(0.f, 0.f, 0.f, 0.f);
}

// ---------- MFMA GEMM, 128x128 tile, BK=64, fused graph epilogue -----------
// mode 1 (GCN): out[M,N] = mix4(A@Bt^T) + bias, ReLU.  gm = A_gcn.
// mode 2 (SAGE): Bt interleaved [Wl|Wr]; writes h_un[M,F=N/2] = mix4(h@Wl)
//   + h@Wr + bias and atomically accumulates per-row sum-of-squares in ssq.
// XCD swizzle: col-blocks of one row-stripe share lin%8 -> same XCD L2.
__global__ __launch_bounds__(256, 4) void gemm_mfma(
    const bf16* __restrict__ A, int K,
    const bf16* __restrict__ Bt,
    const float* __restrict__ bias,
    bf16* __restrict__ out, int N, int mode,
    const float* __restrict__ gm, float* __restrict__ ssq) {
    __shared__ bf16 sA[8192];   // 16 frags x 512 elems (16 rows x 32 k each)
    __shared__ bf16 sB[8192];
    const int t = threadIdx.x;
    const int lane = t & 63;
    const int w = t >> 6;
    const int wr = w >> 1, wc = w & 1;
    // XCD-aware swizzle (requires gridDim.y % 8 == 0)
    const int lin = blockIdx.x + gridDim.x * blockIdx.y;
    const int C = gridDim.x;
    const int cls = lin & 7;
    const int s = lin >> 3;
    const int rpc = gridDim.y >> 3;
    const int sy = s / C;
    const int row0 = (cls * rpc + sy) * 128;
    const int col0 = (s - sy * C) * 128;
    const int fm = lane & 15;   // m (or n) within 16x16 fragment
    const int fq = lane >> 4;   // k-chunk: k = fq*8 + j

    f32x4 acc[4][4] = {};

    const size_t rA0 = (size_t)(row0 + w * 16 + fm) * K;
    const size_t rA1 = (size_t)(row0 + (w + 4) * 16 + fm) * K;
    const size_t rB0 = (size_t)(col0 + w * 16 + fm) * K;
    const size_t rB1 = (size_t)(col0 + (w + 4) * 16 + fm) * K;

    for (int kb = 0; kb < K; kb += 64) {
        int ka = kb + fq * 8;
        glds16(A  + rA0 + ka,      &sA[w * 512]);
        glds16(A  + rA1 + ka,      &sA[(w + 4) * 512]);
        glds16(A  + rA0 + ka + 32, &sA[(8 + w) * 512]);
        glds16(A  + rA1 + ka + 32, &sA[(12 + w) * 512]);
        glds16(Bt + rB0 + ka,      &sB[w * 512]);
        glds16(Bt + rB1 + ka,      &sB[(w + 4) * 512]);
        glds16(Bt + rB0 + ka + 32, &sB[(8 + w) * 512]);
        glds16(Bt + rB1 + ka + 32, &sB[(12 + w) * 512]);
        __syncthreads();
#pragma unroll
        for (int h = 0; h < 2; h++) {
            bf16x8 af[4], bfr[4];
#pragma unroll
            for (int i = 0; i < 4; i++) {
                af[i]  = *(const bf16x8*)&sA[(h * 8 + wr * 4 + i) * 512 + lane * 8];
                bfr[i] = *(const bf16x8*)&sB[(h * 8 + wc * 4 + i) * 512 + lane * 8];
            }
#pragma unroll
            for (int i = 0; i < 4; i++)
#pragma unroll
                for (int j = 0; j < 4; j++)
                    acc[i][j] = __builtin_amdgcn_mfma_f32_16x16x32_bf16(af[i], bfr[j], acc[i][j], 0, 0, 0);
        }
        __syncthreads();
    }

    float g[16];
#pragma unroll
    for (int q = 0; q < 16; q++) g[q] = gm[q];

    if (mode == 1) {
        // GCN: in-register 4x4 node mix + bias + ReLU (acc[..][v] = group rows)
#pragma unroll
        for (int j = 0; j < 4; j++) {
            int c = col0 + wc * 64 + j * 16 + fm;
            float bsv = bias[c];
#pragma unroll
            for (int i = 0; i < 4; i++) {
                int r0 = row0 + wr * 64 + i * 16 + fq * 4;
#pragma unroll
                for (int n = 0; n < 4; n++) {
                    float v = g[n * 4 + 0] * acc[i][j][0] + g[n * 4 + 1] * acc[i][j][1] +
                              g[n * 4 + 2] * acc[i][j][2] + g[n * 4 + 3] * acc[i][j][3] + bsv;
                    out[(size_t)(r0 + n) * N + c] = (bf16)fmaxf(v, 0.f);
                }
            }
        }
    } else {
        // SAGE: even lane = Wl col f (mix), odd lane = Wr col f (self); pair-exchange
        const int F = N >> 1;
        const bool ev = ((lane & 1) == 0);
#pragma unroll
        for (int i = 0; i < 4; i++) {
            int r0 = row0 + wr * 64 + i * 16 + fq * 4;
            float ssql[4] = {0.f, 0.f, 0.f, 0.f};
#pragma unroll
            for (int j = 0; j < 4; j++) {
                int c = col0 + wc * 64 + j * 16 + fm;
                int f = c >> 1;
                float bsv = bias[f];
                float mine[4];
                if (ev) {
#pragma unroll
                    for (int n = 0; n < 4; n++)
                        mine[n] = g[n * 4 + 0] * acc[i][j][0] + g[n * 4 + 1] * acc[i][j][1] +
                                  g[n * 4 + 2] * acc[i][j][2] + g[n * 4 + 3] * acc[i][j][3];
                } else {
#pragma unroll
                    for (int n = 0; n < 4; n++) mine[n] = acc[i][j][n];
                }
#pragma unroll
                for (int n = 0; n < 4; n++) {
                    float oth = __shfl_xor(mine[n], 1);
                    float tot = mine[n] + oth + bsv;
                    ssql[n] += tot * tot;
                    if (ev) out[(size_t)(r0 + n) * F + f] = (bf16)tot;
                }
            }
            // reduce ssq over the 16-lane fm group (pairs duplicate -> x0.5)
#pragma unroll
            for (int n = 0; n < 4; n++) {
                float v = ssql[n];
                v += __shfl_xor(v, 1); v += __shfl_xor(v, 2);
                v += __shfl_xor(v, 4); v += __shfl_xor(v, 8);
                ssql[n] = v;
            }
            if ((lane & 15) == 0) {
#pragma unroll
                for (int n = 0; n < 4; n++) atomicAdd(&ssq[r0 + n], ssql[n] * 0.5f);
            }
        }
    }
}

// ---------- apply L2-norm (from ssq) + ReLU, in place ----------------------
__global__ __launch_bounds__(256) void norm_apply(bf16x8* __restrict__ h,
                                                  const float* __restrict__ ssq,
                                                  int shift) {
    int idx = blockIdx.x * 256 + threadIdx.x;
    int row = idx >> shift;
    float inv = 1.f / fmaxf(sqrtf(ssq[row]), 1e-12f);
    bf16x8 v = h[idx], o;
#pragma unroll
    for (int c = 0; c < 8; c++) o[c] = (bf16)fmaxf((float)v[c] * inv, 0.f);
    h[idx] = o;
}

// ---------- final FC (1024 -> 10) + softmax; one wave per batch element ----
__global__ __launch_bounds__(256) void fc_softmax(const bf16x8* __restrict__ h,
                                                  const float* __restrict__ Wfc,
                                                  const float* __restrict__ bfc,
                                                  float* __restrict__ outp) {
    __shared__ float WT[10][1024];
    int t = threadIdx.x;
    for (int i = t; i < 10240; i += 256) { int o = i % 10, k = i / 10; WT[o][k] = Wfc[i]; }
    __syncthreads();
    int wid = t >> 6, lane = t & 63;
    size_t e = (size_t)blockIdx.x * 4 + wid;
    const bf16x8* hp = h + e * 128;
    float acc[10];
#pragma unroll
    for (int o = 0; o < 10; o++) acc[o] = 0.f;
#pragma unroll
    for (int j = 0; j < 2; j++) {
        int ch = j * 64 + lane;
        bf16x8 v = hp[ch];
        float f[8];
#pragma unroll
        for (int c = 0; c < 8; c++) f[c] = (float)v[c];
        int k0 = ch * 8;
#pragma unroll
        for (int o = 0; o < 10; o++) {
            const float* wr = &WT[o][k0];
            float s = 0.f;
#pragma unroll
            for (int c = 0; c < 8; c++) s += f[c] * wr[c];
            acc[o] += s;
        }
    }
#pragma unroll
    for (int o = 0; o < 10; o++) {
        float v = acc[o];
        v += __shfl_xor(v, 32); v += __shfl_xor(v, 16); v += __shfl_xor(v, 8);
        v += __shfl_xor(v, 4);  v += __shfl_xor(v, 2);  v += __shfl_xor(v, 1);
        acc[o] = v + bfc[o];
    }
    float mx = acc[0];
#pragma unroll
    for (int o = 1; o < 10; o++) mx = fmaxf(mx, acc[o]);
    float sum = 0.f, p[10];
#pragma unroll
    for (int o = 0; o < 10; o++) { p[o] = expf(acc[o] - mx); sum += p[o]; }
    float inv = 1.f / sum;
    if (lane < 10) outp[e * 10 + lane] = p[lane] * inv;
}

// ---------------------------------------------------------------------------
extern "C" void kernel_launch(void* const* d_in, const int* in_sizes, int n_in,
                              void* d_out, int out_size, void* d_ws, size_t ws_size,
                              hipStream_t stream) {
    const float* x   = (const float*)d_in[0];
    const int*   ei  = (const int*)d_in[1];
    const float* W1  = (const float*)d_in[2];
    const float* b1  = (const float*)d_in[3];
    const float* Wl2 = (const float*)d_in[4];
    const float* bl2 = (const float*)d_in[5];
    const float* Wr2 = (const float*)d_in[6];
    const float* Wl3 = (const float*)d_in[7];
    const float* bl3 = (const float*)d_in[8];
    const float* Wr3 = (const float*)d_in[9];
    const float* Wl4 = (const float*)d_in[10];
    const float* bl4 = (const float*)d_in[11];
    const float* Wr4 = (const float*)d_in[12];
    const float* Wfc = (const float*)d_in[13];
    const float* bfc = (const float*)d_in[14];
    float* out = (float*)d_out;

    const int B = 32768;
    char* base = (char*)d_ws;
    float* gmat = (float*)base;
    bf16* Wt1 = (bf16*)(base + 4096);                  // [1024 x 64]
    bf16* Wt2 = Wt1 + 1024 * 64;                       // [1024 x 1024] interleaved Wl2/Wr2
    bf16* Wt3 = Wt2 + 1024 * 1024;                     // [512 x 512]  interleaved
    bf16* Wt4 = Wt3 + 512 * 512;                       // [512 x 256]  interleaved
    char* sl  = (char*)(Wt4 + 512 * 256);
    size_t fixed = (size_t)(sl - base);

    // per-elem: bf16 (256+4096+4096)=8448 -> 16896 B, + ssq 3 rows x 4 x 4B = 48 B
    int Bs = B;
    while (Bs > 512 && fixed + (size_t)Bs * 16944 > ws_size) Bs >>= 1;
    int nslice = B / Bs;
    int M = Bs * 4;

    bf16* R0 = (bf16*)sl;                       // xb  [M,64]
    bf16* R1 = R0 + (size_t)Bs * 256;           // h1 [M,1024]; then h3 [M,256]
    bf16* R2 = R1 + (size_t)Bs * 4096;          // h2 [M,512]; then h4 [M,256]
    float* ssqb = (float*)(R2 + (size_t)Bs * 4096);   // 3*M floats

    hipLaunchKernelGGL(k_setup, dim3(1), dim3(64), 0, stream, ei, gmat);
    hipLaunchKernelGGL(wtrans, dim3((1024 * 64 + 255) / 256), dim3(256), 0, stream,
                       W1, 64, 1024, Wt1);
    hipLaunchKernelGGL(wtransI, dim3((1024 * 1024 + 255) / 256), dim3(256), 0, stream,
                       Wl2, Wr2, 1024, 512, Wt2);
    hipLaunchKernelGGL(wtransI, dim3((512 * 512 + 255) / 256), dim3(256), 0, stream,
                       Wl3, Wr3, 512, 256, Wt3);
    hipLaunchKernelGGL(wtransI, dim3((512 * 256 + 255) / 256), dim3(256), 0, stream,
                       Wl4, Wr4, 256, 256, Wt4);

    for (int s = 0; s < nslice; s++) {
        const float* xs = x + (size_t)s * Bs * 256;
        hipLaunchKernelGGL(k_zero, dim3((3 * M / 4 + 255) / 256), dim3(256), 0, stream,
                           (float4*)ssqb, 3 * M / 4);
        // cast x -> bf16
        hipLaunchKernelGGL(cast_x, dim3(Bs / 8), dim3(256), 0, stream,
                           (const float4*)xs, (bf16x8*)R0);
        // L1 GCN: h1 = relu(mix(x@W1) + b1)   [mode 1]
        hipLaunchKernelGGL(gemm_mfma, dim3(8, M / 128), dim3(256), 0, stream,
                           R0, 64, Wt1, b1, R1, 1024, 1, gmat, (float*)nullptr);
        // L2 SAGE: h2_un = mix(h1@Wl2) + h1@Wr2 + bl2 (F=512) + ssq  [mode 2]
        hipLaunchKernelGGL(gemm_mfma, dim3(8, M / 128), dim3(256), 0, stream,
                           R1, 1024, Wt2, bl2, R2, 1024, 2, gmat + 16, ssqb);
        hipLaunchKernelGGL(norm_apply, dim3(M / 4), dim3(256), 0, stream,
                           (bf16x8*)R2, ssqb, 6);           // M*64/256 = M/4 blocks
        // L3 SAGE: h3_un (F=256) into R1
        hipLaunchKernelGGL(gemm_mfma, dim3(4, M / 128), dim3(256), 0, stream,
                           R2, 512, Wt3, bl3, R1, 512, 2, gmat + 16, ssqb + M);
        hipLaunchKernelGGL(norm_apply, dim3(M / 8), dim3(256), 0, stream,
                           (bf16x8*)R1, ssqb + M, 5);       // M*32/256 = M/8 blocks
        // L4 SAGE: h4_un (F=256) into R2
        hipLaunchKernelGGL(gemm_mfma, dim3(4, M / 128), dim3(256), 0, stream,
                           R1, 256, Wt4, bl4, R2, 512, 2, gmat + 16, ssqb + 2 * M);
        hipLaunchKernelGGL(norm_apply, dim3(M / 8), dim3(256), 0, stream,
                           (bf16x8*)R2, ssqb + 2 * M, 5);
        // FC + softmax (reads h4 in R2)
        hipLaunchKernelGGL(fc_softmax, dim3(Bs / 4), dim3(256), 0, stream,
                           (const bf16x8*)R2, Wfc, bfc, out + (size_t)s * Bs * 10);
    }
}

// Round 7
// 1157.050 us; speedup vs baseline: 6.1139x; 1.0500x over previous
//
#include <hip/hip_runtime.h>
#include <stdint.h>
#include <math.h>

typedef __bf16 bf16;
typedef __attribute__((ext_vector_type(8))) __bf16 bf16x8;
typedef __attribute__((ext_vector_type(4))) float f32x4;

#define AS1 __attribute__((address_space(1)))
#define AS3 __attribute__((address_space(3)))

__device__ __forceinline__ void glds16(const void* g, void* l) {
    __builtin_amdgcn_global_load_lds((const AS1 uint32_t*)g, (AS3 uint32_t*)l, 16, 0, 0);
}

// ---------- setup: A_gcn (gmat[0..15]) and M_sage (gmat[16..31]) -----------
__global__ void k_setup(const int* __restrict__ ei, float* __restrict__ gmat) {
    if (threadIdx.x != 0 || blockIdx.x != 0) return;
    bool is64 = true;
    for (int i = 0; i < 12; i++) if (ei[2 * i + 1] != 0) { is64 = false; break; }
    int src[12], dst[12];
    for (int e = 0; e < 12; e++) {
        if (is64) { src[e] = ei[2 * e]; dst[e] = ei[24 + 2 * e]; }
        else      { src[e] = ei[e];     dst[e] = ei[12 + e]; }
    }
    float deg[4] = {1.f, 1.f, 1.f, 1.f};
    for (int e = 0; e < 12; e++) deg[dst[e]] += 1.f;
    float dinv[4];
    for (int n = 0; n < 4; n++) dinv[n] = 1.f / sqrtf(deg[n]);
    float A[16];
    for (int i = 0; i < 16; i++) A[i] = 0.f;
    for (int e = 0; e < 12; e++) A[dst[e] * 4 + src[e]] += dinv[src[e]] * dinv[dst[e]];
    for (int n = 0; n < 4; n++) A[n * 4 + n] += dinv[n] * dinv[n];
    float cnt[4] = {0.f, 0.f, 0.f, 0.f};
    for (int e = 0; e < 12; e++) cnt[dst[e]] += 1.f;
    for (int n = 0; n < 4; n++) cnt[n] = fmaxf(cnt[n], 1.f);
    float Mm[16];
    for (int i = 0; i < 16; i++) Mm[i] = 0.f;
    for (int e = 0; e < 12; e++) Mm[dst[e] * 4 + src[e]] += 1.f;
    for (int n = 0; n < 4; n++)
        for (int m = 0; m < 4; m++) Mm[n * 4 + m] /= cnt[n];
    for (int i = 0; i < 16; i++) { gmat[i] = A[i]; gmat[16 + i] = Mm[i]; }
}

// ---------- Wt1: transpose W [K,N] -> Bt [N,K] bf16 ------------------------
__global__ __launch_bounds__(256) void wtrans(const float* __restrict__ W, int K,
                                              int N, bf16* __restrict__ Wt) {
    int idx = blockIdx.x * 256 + threadIdx.x;
    if (idx >= N * K) return;
    int n = idx / K, k = idx - n * K;
    Wt[idx] = (bf16)W[(size_t)k * N + n];
}

// ---------- interleaved stack: Bt[2F,K]; row 2f -> Wl col f, 2f+1 -> Wr ----
__global__ __launch_bounds__(256) void wtransI(const float* __restrict__ Wl,
                                               const float* __restrict__ Wr,
                                               int K, int F, bf16* __restrict__ Bt) {
    int idx = blockIdx.x * 256 + threadIdx.x;
    if (idx >= 2 * F * K) return;
    int n = idx / K, k = idx - n * K;
    int f = n >> 1;
    float v = (n & 1) ? Wr[(size_t)k * F + f] : Wl[(size_t)k * F + f];
    Bt[idx] = (bf16)v;
}

// ---------- cast fp32 x -> bf16 --------------------------------------------
__global__ __launch_bounds__(256) void cast_x(const float4* __restrict__ x,
                                              bf16x8* __restrict__ out) {
    int i = blockIdx.x * 256 + threadIdx.x;
    float4 a = x[2 * i], b = x[2 * i + 1];
    bf16x8 o;
    o[0] = (bf16)a.x; o[1] = (bf16)a.y; o[2] = (bf16)a.z; o[3] = (bf16)a.w;
    o[4] = (bf16)b.x; o[5] = (bf16)b.y; o[6] = (bf16)b.z; o[7] = (bf16)b.w;
    out[i] = o;
}

// ---------- zero ssq accumulators ------------------------------------------
__global__ __launch_bounds__(256) void k_zero(float4* __restrict__ p, int n4) {
    int i = blockIdx.x * 256 + threadIdx.x;
    if (i < n4) p[i] = make_float4(0.f, 0.f, 0.f, 0.f);
}

// ---------- MFMA GEMM, 128x256 tile, BK=64, fused graph epilogue -----------
// mode 1 (GCN): out[M,N] = mix4(A@Bt^T) + bias, ReLU.  gm = A_gcn.
// mode 2 (SAGE): Bt interleaved [Wl|Wr]; writes h_un[M,F=N/2] = mix4(h@Wl)
//   + h@Wr + bias and atomically accumulates per-row sum-of-squares in ssq.
// XCD swizzle: col-blocks of one row-stripe share lin%8 -> same XCD L2.
// 4 waves: wr=row-half (64 rows), wc=col-half (128 cols); acc 4x8 f32x4.
__global__ __launch_bounds__(256, 2) void gemm_mfma(
    const bf16* __restrict__ A, int K,
    const bf16* __restrict__ Bt,
    const float* __restrict__ bias,
    bf16* __restrict__ out, int N, int mode,
    const float* __restrict__ gm, float* __restrict__ ssq) {
    __shared__ bf16 sA[8192];    // 16 slots (2 kHalf x 8 rowBlk) x 512
    __shared__ bf16 sB[16384];   // 32 slots (2 kHalf x 16 colBlk) x 512
    const int t = threadIdx.x;
    const int lane = t & 63;
    const int w = t >> 6;
    const int wr = w >> 1, wc = w & 1;
    // XCD-aware swizzle (requires gridDim.y % 8 == 0)
    const int lin = blockIdx.x + gridDim.x * blockIdx.y;
    const int C = gridDim.x;
    const int cls = lin & 7;
    const int s = lin >> 3;
    const int rpc = gridDim.y >> 3;
    const int sy = s / C;
    const int row0 = (cls * rpc + sy) * 128;
    const int col0 = (s - sy * C) * 256;
    const int fm = lane & 15;   // m (or n) within 16x16 fragment
    const int fq = lane >> 4;   // k-chunk: k = fq*8 + j

    f32x4 acc[4][8] = {};

    const size_t rA0 = (size_t)(row0 + w * 16 + fm) * K;
    const size_t rA1 = (size_t)(row0 + (w + 4) * 16 + fm) * K;
    const size_t rB0 = (size_t)(col0 + (w + 0) * 16 + fm) * K;
    const size_t rB1 = (size_t)(col0 + (w + 4) * 16 + fm) * K;
    const size_t rB2 = (size_t)(col0 + (w + 8) * 16 + fm) * K;
    const size_t rB3 = (size_t)(col0 + (w + 12) * 16 + fm) * K;

    for (int kb = 0; kb < K; kb += 64) {
        int ka = kb + fq * 8;
        // A: rowBlks {w, w+4}, both k-halves
        glds16(A + rA0 + ka,       &sA[(0 * 8 + w) * 512]);
        glds16(A + rA1 + ka,       &sA[(0 * 8 + w + 4) * 512]);
        glds16(A + rA0 + ka + 32,  &sA[(1 * 8 + w) * 512]);
        glds16(A + rA1 + ka + 32,  &sA[(1 * 8 + w + 4) * 512]);
        // B: colBlks {w, w+4, w+8, w+12}, both k-halves
        glds16(Bt + rB0 + ka,      &sB[(0 * 16 + w + 0) * 512]);
        glds16(Bt + rB1 + ka,      &sB[(0 * 16 + w + 4) * 512]);
        glds16(Bt + rB2 + ka,      &sB[(0 * 16 + w + 8) * 512]);
        glds16(Bt + rB3 + ka,      &sB[(0 * 16 + w + 12) * 512]);
        glds16(Bt + rB0 + ka + 32, &sB[(1 * 16 + w + 0) * 512]);
        glds16(Bt + rB1 + ka + 32, &sB[(1 * 16 + w + 4) * 512]);
        glds16(Bt + rB2 + ka + 32, &sB[(1 * 16 + w + 8) * 512]);
        glds16(Bt + rB3 + ka + 32, &sB[(1 * 16 + w + 12) * 512]);
        __syncthreads();
#pragma unroll
        for (int h = 0; h < 2; h++) {
            bf16x8 af[4], bfr[8];
#pragma unroll
            for (int i = 0; i < 4; i++)
                af[i] = *(const bf16x8*)&sA[(h * 8 + wr * 4 + i) * 512 + lane * 8];
#pragma unroll
            for (int j = 0; j < 8; j++)
                bfr[j] = *(const bf16x8*)&sB[(h * 16 + wc * 8 + j) * 512 + lane * 8];
#pragma unroll
            for (int i = 0; i < 4; i++)
#pragma unroll
                for (int j = 0; j < 8; j++)
                    acc[i][j] = __builtin_amdgcn_mfma_f32_16x16x32_bf16(af[i], bfr[j], acc[i][j], 0, 0, 0);
        }
        __syncthreads();
    }

    float g[16];
#pragma unroll
    for (int q = 0; q < 16; q++) g[q] = gm[q];

    if (mode == 1) {
        // GCN: in-register 4x4 node mix + bias + ReLU (acc[..][v] = group rows)
#pragma unroll
        for (int j = 0; j < 8; j++) {
            int c = col0 + wc * 128 + j * 16 + fm;
            float bsv = bias[c];
#pragma unroll
            for (int i = 0; i < 4; i++) {
                int r0 = row0 + wr * 64 + i * 16 + fq * 4;
#pragma unroll
                for (int n = 0; n < 4; n++) {
                    float v = g[n * 4 + 0] * acc[i][j][0] + g[n * 4 + 1] * acc[i][j][1] +
                              g[n * 4 + 2] * acc[i][j][2] + g[n * 4 + 3] * acc[i][j][3] + bsv;
                    out[(size_t)(r0 + n) * N + c] = (bf16)fmaxf(v, 0.f);
                }
            }
        }
    } else {
        // SAGE: even lane = Wl col f (mix), odd lane = Wr col f (self); pair-exchange
        const int F = N >> 1;
        const bool ev = ((lane & 1) == 0);
#pragma unroll
        for (int i = 0; i < 4; i++) {
            int r0 = row0 + wr * 64 + i * 16 + fq * 4;
            float ssql[4] = {0.f, 0.f, 0.f, 0.f};
#pragma unroll
            for (int j = 0; j < 8; j++) {
                int c = col0 + wc * 128 + j * 16 + fm;
                int f = c >> 1;
                float bsv = bias[f];
                float mine[4];
                if (ev) {
#pragma unroll
                    for (int n = 0; n < 4; n++)
                        mine[n] = g[n * 4 + 0] * acc[i][j][0] + g[n * 4 + 1] * acc[i][j][1] +
                                  g[n * 4 + 2] * acc[i][j][2] + g[n * 4 + 3] * acc[i][j][3];
                } else {
#pragma unroll
                    for (int n = 0; n < 4; n++) mine[n] = acc[i][j][n];
                }
#pragma unroll
                for (int n = 0; n < 4; n++) {
                    float oth = __shfl_xor(mine[n], 1);
                    float tot = mine[n] + oth + bsv;
                    ssql[n] += tot * tot;
                    if (ev) out[(size_t)(r0 + n) * F + f] = (bf16)tot;
                }
            }
            // reduce ssq over the 16-lane fm group (pairs duplicate -> x0.5)
#pragma unroll
            for (int n = 0; n < 4; n++) {
                float v = ssql[n];
                v += __shfl_xor(v, 1); v += __shfl_xor(v, 2);
                v += __shfl_xor(v, 4); v += __shfl_xor(v, 8);
                ssql[n] = v;
            }
            if ((lane & 15) == 0) {
#pragma unroll
                for (int n = 0; n < 4; n++) atomicAdd(&ssq[r0 + n], ssql[n] * 0.5f);
            }
        }
    }
}

// ---------- apply L2-norm (from ssq) + ReLU, in place ----------------------
__global__ __launch_bounds__(256) void norm_apply(bf16x8* __restrict__ h,
                                                  const float* __restrict__ ssq,
                                                  int shift) {
    int idx = blockIdx.x * 256 + threadIdx.x;
    int row = idx >> shift;
    float inv = 1.f / fmaxf(sqrtf(ssq[row]), 1e-12f);
    bf16x8 v = h[idx], o;
#pragma unroll
    for (int c = 0; c < 8; c++) o[c] = (bf16)fmaxf((float)v[c] * inv, 0.f);
    h[idx] = o;
}

// ---------- final FC (1024 -> 10) + softmax; one wave per batch element ----
__global__ __launch_bounds__(256) void fc_softmax(const bf16x8* __restrict__ h,
                                                  const float* __restrict__ Wfc,
                                                  const float* __restrict__ bfc,
                                                  float* __restrict__ outp) {
    __shared__ float WT[10][1024];
    int t = threadIdx.x;
    for (int i = t; i < 10240; i += 256) { int o = i % 10, k = i / 10; WT[o][k] = Wfc[i]; }
    __syncthreads();
    int wid = t >> 6, lane = t & 63;
    size_t e = (size_t)blockIdx.x * 4 + wid;
    const bf16x8* hp = h + e * 128;
    float acc[10];
#pragma unroll
    for (int o = 0; o < 10; o++) acc[o] = 0.f;
#pragma unroll
    for (int j = 0; j < 2; j++) {
        int ch = j * 64 + lane;
        bf16x8 v = hp[ch];
        float f[8];
#pragma unroll
        for (int c = 0; c < 8; c++) f[c] = (float)v[c];
        int k0 = ch * 8;
#pragma unroll
        for (int o = 0; o < 10; o++) {
            const float* wr = &WT[o][k0];
            float s = 0.f;
#pragma unroll
            for (int c = 0; c < 8; c++) s += f[c] * wr[c];
            acc[o] += s;
        }
    }
#pragma unroll
    for (int o = 0; o < 10; o++) {
        float v = acc[o];
        v += __shfl_xor(v, 32); v += __shfl_xor(v, 16); v += __shfl_xor(v, 8);
        v += __shfl_xor(v, 4);  v += __shfl_xor(v, 2);  v += __shfl_xor(v, 1);
        acc[o] = v + bfc[o];
    }
    float mx = acc[0];
#pragma unroll
    for (int o = 1; o < 10; o++) mx = fmaxf(mx, acc[o]);
    float sum = 0.f, p[10];
#pragma unroll
    for (int o = 0; o < 10; o++) { p[o] = expf(acc[o] - mx); sum += p[o]; }
    float inv = 1.f / sum;
    if (lane < 10) outp[e * 10 + lane] = p[lane] * inv;
}

// ---------------------------------------------------------------------------
extern "C" void kernel_launch(void* const* d_in, const int* in_sizes, int n_in,
                              void* d_out, int out_size, void* d_ws, size_t ws_size,
                              hipStream_t stream) {
    const float* x   = (const float*)d_in[0];
    const int*   ei  = (const int*)d_in[1];
    const float* W1  = (const float*)d_in[2];
    const float* b1  = (const float*)d_in[3];
    const float* Wl2 = (const float*)d_in[4];
    const float* bl2 = (const float*)d_in[5];
    const float* Wr2 = (const float*)d_in[6];
    const float* Wl3 = (const float*)d_in[7];
    const float* bl3 = (const float*)d_in[8];
    const float* Wr3 = (const float*)d_in[9];
    const float* Wl4 = (const float*)d_in[10];
    const float* bl4 = (const float*)d_in[11];
    const float* Wr4 = (const float*)d_in[12];
    const float* Wfc = (const float*)d_in[13];
    const float* bfc = (const float*)d_in[14];
    float* out = (float*)d_out;

    const int B = 32768;
    char* base = (char*)d_ws;
    float* gmat = (float*)base;
    bf16* Wt1 = (bf16*)(base + 4096);                  // [1024 x 64]
    bf16* Wt2 = Wt1 + 1024 * 64;                       // [1024 x 1024] interleaved Wl2/Wr2
    bf16* Wt3 = Wt2 + 1024 * 1024;                     // [512 x 512]  interleaved
    bf16* Wt4 = Wt3 + 512 * 512;                       // [512 x 256]  interleaved
    char* sl  = (char*)(Wt4 + 512 * 256);
    size_t fixed = (size_t)(sl - base);

    // per-elem: bf16 (256+4096+4096)=8448 -> 16896 B, + ssq 3 rows x 4 x 4B = 48 B
    int Bs = B;
    while (Bs > 512 && fixed + (size_t)Bs * 16944 > ws_size) Bs >>= 1;
    int nslice = B / Bs;
    int M = Bs * 4;

    bf16* R0 = (bf16*)sl;                       // xb  [M,64]
    bf16* R1 = R0 + (size_t)Bs * 256;           // h1 [M,1024]; then h3 [M,256]
    bf16* R2 = R1 + (size_t)Bs * 4096;          // h2 [M,512]; then h4 [M,256]
    float* ssqb = (float*)(R2 + (size_t)Bs * 4096);   // 3*M floats

    hipLaunchKernelGGL(k_setup, dim3(1), dim3(64), 0, stream, ei, gmat);
    hipLaunchKernelGGL(wtrans, dim3((1024 * 64 + 255) / 256), dim3(256), 0, stream,
                       W1, 64, 1024, Wt1);
    hipLaunchKernelGGL(wtransI, dim3((1024 * 1024 + 255) / 256), dim3(256), 0, stream,
                       Wl2, Wr2, 1024, 512, Wt2);
    hipLaunchKernelGGL(wtransI, dim3((512 * 512 + 255) / 256), dim3(256), 0, stream,
                       Wl3, Wr3, 512, 256, Wt3);
    hipLaunchKernelGGL(wtransI, dim3((512 * 256 + 255) / 256), dim3(256), 0, stream,
                       Wl4, Wr4, 256, 256, Wt4);

    for (int s = 0; s < nslice; s++) {
        const float* xs = x + (size_t)s * Bs * 256;
        hipLaunchKernelGGL(k_zero, dim3((3 * M / 4 + 255) / 256), dim3(256), 0, stream,
                           (float4*)ssqb, 3 * M / 4);
        // cast x -> bf16
        hipLaunchKernelGGL(cast_x, dim3(Bs / 8), dim3(256), 0, stream,
                           (const float4*)xs, (bf16x8*)R0);
        // L1 GCN: h1 = relu(mix(x@W1) + b1)   [mode 1]  N=1024, K=64
        hipLaunchKernelGGL(gemm_mfma, dim3(4, M / 128), dim3(256), 0, stream,
                           R0, 64, Wt1, b1, R1, 1024, 1, gmat, (float*)nullptr);
        // L2 SAGE: h2_un (F=512) + ssq  [mode 2]  N=1024, K=1024
        hipLaunchKernelGGL(gemm_mfma, dim3(4, M / 128), dim3(256), 0, stream,
                           R1, 1024, Wt2, bl2, R2, 1024, 2, gmat + 16, ssqb);
        hipLaunchKernelGGL(norm_apply, dim3(M / 4), dim3(256), 0, stream,
                           (bf16x8*)R2, ssqb, 6);           // M*64/256 = M/4 blocks
        // L3 SAGE: h3_un (F=256) into R1   N=512, K=512
        hipLaunchKernelGGL(gemm_mfma, dim3(2, M / 128), dim3(256), 0, stream,
                           R2, 512, Wt3, bl3, R1, 512, 2, gmat + 16, ssqb + M);
        hipLaunchKernelGGL(norm_apply, dim3(M / 8), dim3(256), 0, stream,
                           (bf16x8*)R1, ssqb + M, 5);       // M*32/256 = M/8 blocks
        // L4 SAGE: h4_un (F=256) into R2   N=512, K=256
        hipLaunchKernelGGL(gemm_mfma, dim3(2, M / 128), dim3(256), 0, stream,
                           R1, 256, Wt4, bl4, R2, 512, 2, gmat + 16, ssqb + 2 * M);
        hipLaunchKernelGGL(norm_apply, dim3(M / 8), dim3(256), 0, stream,
                           (bf16x8*)R2, ssqb + 2 * M, 5);
        // FC + softmax (reads h4 in R2)
        hipLaunchKernelGGL(fc_softmax, dim3(Bs / 4), dim3(256), 0, stream,
                           (const bf16x8*)R2, Wfc, bfc, out + (size_t)s * Bs * 10);
    }
}

// Round 10
// 1099.267 us; speedup vs baseline: 6.4353x; 1.0526x over previous
//
#include <hip/hip_runtime.h>
#include <stdint.h>
#include <math.h>

typedef __bf16 bf16;
typedef __attribute__((ext_vector_type(8))) __bf16 bf16x8;
typedef __attribute__((ext_vector_type(16))) float f32x16;

#define AS1 __attribute__((address_space(1)))
#define AS3 __attribute__((address_space(3)))

__device__ __forceinline__ void glds16(const void* g, void* l) {
    __builtin_amdgcn_global_load_lds((const AS1 uint32_t*)g, (AS3 uint32_t*)l, 16, 0, 0);
}

// ---------- setup: A_gcn (gmat[0..15]) and M_sage (gmat[16..31]) -----------
__global__ void k_setup(const int* __restrict__ ei, float* __restrict__ gmat) {
    if (threadIdx.x != 0 || blockIdx.x != 0) return;
    bool is64 = true;
    for (int i = 0; i < 12; i++) if (ei[2 * i + 1] != 0) { is64 = false; break; }
    int src[12], dst[12];
    for (int e = 0; e < 12; e++) {
        if (is64) { src[e] = ei[2 * e]; dst[e] = ei[24 + 2 * e]; }
        else      { src[e] = ei[e];     dst[e] = ei[12 + e]; }
    }
    float deg[4] = {1.f, 1.f, 1.f, 1.f};
    for (int e = 0; e < 12; e++) deg[dst[e]] += 1.f;
    float dinv[4];
    for (int n = 0; n < 4; n++) dinv[n] = 1.f / sqrtf(deg[n]);
    float A[16];
    for (int i = 0; i < 16; i++) A[i] = 0.f;
    for (int e = 0; e < 12; e++) A[dst[e] * 4 + src[e]] += dinv[src[e]] * dinv[dst[e]];
    for (int n = 0; n < 4; n++) A[n * 4 + n] += dinv[n] * dinv[n];
    float cnt[4] = {0.f, 0.f, 0.f, 0.f};
    for (int e = 0; e < 12; e++) cnt[dst[e]] += 1.f;
    for (int n = 0; n < 4; n++) cnt[n] = fmaxf(cnt[n], 1.f);
    float Mm[16];
    for (int i = 0; i < 16; i++) Mm[i] = 0.f;
    for (int e = 0; e < 12; e++) Mm[dst[e] * 4 + src[e]] += 1.f;
    for (int n = 0; n < 4; n++)
        for (int m = 0; m < 4; m++) Mm[n * 4 + m] /= cnt[n];
    for (int i = 0; i < 16; i++) { gmat[i] = A[i]; gmat[16 + i] = Mm[i]; }
}

// ---------- Wt1: transpose W [K,N] -> Bt [N,K] bf16 ------------------------
__global__ __launch_bounds__(256) void wtrans(const float* __restrict__ W, int K,
                                              int N, bf16* __restrict__ Wt) {
    int idx = blockIdx.x * 256 + threadIdx.x;
    if (idx >= N * K) return;
    int n = idx / K, k = idx - n * K;
    Wt[idx] = (bf16)W[(size_t)k * N + n];
}

// ---------- interleaved stack: Bt[2F,K]; row 2f -> Wl col f, 2f+1 -> Wr ----
__global__ __launch_bounds__(256) void wtransI(const float* __restrict__ Wl,
                                               const float* __restrict__ Wr,
                                               int K, int F, bf16* __restrict__ Bt) {
    int idx = blockIdx.x * 256 + threadIdx.x;
    if (idx >= 2 * F * K) return;
    int n = idx / K, k = idx - n * K;
    int f = n >> 1;
    float v = (n & 1) ? Wr[(size_t)k * F + f] : Wl[(size_t)k * F + f];
    Bt[idx] = (bf16)v;
}

// ---------- cast fp32 x -> bf16 --------------------------------------------
__global__ __launch_bounds__(256) void cast_x(const float4* __restrict__ x,
                                              bf16x8* __restrict__ out) {
    int i = blockIdx.x * 256 + threadIdx.x;
    float4 a = x[2 * i], b = x[2 * i + 1];
    bf16x8 o;
    o[0] = (bf16)a.x; o[1] = (bf16)a.y; o[2] = (bf16)a.z; o[3] = (bf16)a.w;
    o[4] = (bf16)b.x; o[5] = (bf16)b.y; o[6] = (bf16)b.z; o[7] = (bf16)b.w;
    out[i] = o;
}

// ---------- zero ssq accumulators ------------------------------------------
__global__ __launch_bounds__(256) void k_zero(float4* __restrict__ p, int n4) {
    int i = blockIdx.x * 256 + threadIdx.x;
    if (i < n4) p[i] = make_float4(0.f, 0.f, 0.f, 0.f);
}

// ---------- MFMA GEMM, 128x256 tile, BK=64, 32x32x16 bf16 ------------------
// Barrier-staged (glds16 + __syncthreads, m97-proven). Fragment-ordered LDS.
// A frag: m=lane&31, k=8*(lane>>5)+j. C/D: col=lane&31,
// row=(reg&3)+8*(reg>>2)+4*(lane>>5) -> reg quads = 4 consecutive rows (%4==0).
// mode 1 (GCN): out = mix4(A@Bt^T)+bias, ReLU.
// mode 2 (SAGE, Bt interleaved [Wl|Wr]): h_un[M,F=N/2] + atomic per-row ssq.
__global__ __launch_bounds__(256, 2) void gemm_mfma(
    const bf16* __restrict__ A, int K,
    const bf16* __restrict__ Bt,
    const float* __restrict__ bias,
    bf16* __restrict__ out, int N, int mode,
    const float* __restrict__ gm, float* __restrict__ ssq) {
    __shared__ bf16 sA[8192];    // 16 slots (kslot s*4 + rowblk) x 512 (32r x 16k)
    __shared__ bf16 sB[16384];   // 32 slots (kslot s*8 + colblk) x 512
    const int t = threadIdx.x;
    const int lane = t & 63;
    const int w = t >> 6;
    const int wr = w >> 1, wc = w & 1;
    // XCD-aware swizzle (requires gridDim.y % 8 == 0)
    const int lin = blockIdx.x + gridDim.x * blockIdx.y;
    const int C = gridDim.x;
    const int cls = lin & 7;
    const int s0 = lin >> 3;
    const int rpc = gridDim.y >> 3;
    const int sy = s0 / C;
    const int row0 = (cls * rpc + sy) * 128;
    const int col0 = (s0 - sy * C) * 256;
    const int m32 = lane & 31;   // m (or n) within 32x32 fragment
    const int kh = lane >> 5;    // k-half within 16-k slot: k = kh*8 + j

    f32x16 acc[2][4] = {};

    const size_t rA  = (size_t)(row0 + w * 32 + m32) * K;
    const size_t rB0 = (size_t)(col0 + w * 32 + m32) * K;
    const size_t rB1 = (size_t)(col0 + (w + 4) * 32 + m32) * K;

    for (int kb = 0; kb < K; kb += 64) {
        int ka = kb + kh * 8;
#pragma unroll
        for (int s = 0; s < 4; s++) {
            glds16(A  + rA  + ka + s * 16, &sA[(s * 4 + w) * 512]);
            glds16(Bt + rB0 + ka + s * 16, &sB[(s * 8 + w) * 512]);
            glds16(Bt + rB1 + ka + s * 16, &sB[(s * 8 + w + 4) * 512]);
        }
        __syncthreads();
#pragma unroll
        for (int s = 0; s < 4; s++) {
            bf16x8 af[2], bfr[4];
#pragma unroll
            for (int i = 0; i < 2; i++)
                af[i] = *(const bf16x8*)&sA[(s * 4 + 2 * wr + i) * 512 + lane * 8];
#pragma unroll
            for (int j = 0; j < 4; j++)
                bfr[j] = *(const bf16x8*)&sB[(s * 8 + 4 * wc + j) * 512 + lane * 8];
#pragma unroll
            for (int i = 0; i < 2; i++)
#pragma unroll
                for (int j = 0; j < 4; j++)
                    acc[i][j] = __builtin_amdgcn_mfma_f32_32x32x16_bf16(af[i], bfr[j], acc[i][j], 0, 0, 0);
        }
        __syncthreads();
    }

    float g[16];
#pragma unroll
    for (int q = 0; q < 16; q++) g[q] = gm[q];

    if (mode == 1) {
        // GCN: in-register 4x4 node mix per reg-quad + bias + ReLU
#pragma unroll
        for (int i = 0; i < 2; i++) {
            int rb = row0 + (2 * wr + i) * 32 + 4 * kh;
#pragma unroll
            for (int j = 0; j < 4; j++) {
                int c = col0 + (4 * wc + j) * 32 + m32;
                float bsv = bias[c];
#pragma unroll
                for (int q = 0; q < 4; q++) {
#pragma unroll
                    for (int n = 0; n < 4; n++) {
                        float v = g[n * 4 + 0] * acc[i][j][q * 4 + 0] +
                                  g[n * 4 + 1] * acc[i][j][q * 4 + 1] +
                                  g[n * 4 + 2] * acc[i][j][q * 4 + 2] +
                                  g[n * 4 + 3] * acc[i][j][q * 4 + 3] + bsv;
                        out[(size_t)(rb + 8 * q + n) * N + c] = (bf16)fmaxf(v, 0.f);
                    }
                }
            }
        }
    } else {
        // SAGE: even m32 lane = Wl col f (mix), odd = Wr col f (self)
        const int F = N >> 1;
        const bool ev = ((m32 & 1) == 0);
#pragma unroll
        for (int i = 0; i < 2; i++) {
            int rb = row0 + (2 * wr + i) * 32 + 4 * kh;
#pragma unroll
            for (int q = 0; q < 4; q++) {
                float ssql[4] = {0.f, 0.f, 0.f, 0.f};
#pragma unroll
                for (int j = 0; j < 4; j++) {
                    int c = col0 + (4 * wc + j) * 32 + m32;
                    int f = c >> 1;
                    float bsv = bias[f];
                    float mine[4];
                    if (ev) {
#pragma unroll
                        for (int n = 0; n < 4; n++)
                            mine[n] = g[n * 4 + 0] * acc[i][j][q * 4 + 0] +
                                      g[n * 4 + 1] * acc[i][j][q * 4 + 1] +
                                      g[n * 4 + 2] * acc[i][j][q * 4 + 2] +
                                      g[n * 4 + 3] * acc[i][j][q * 4 + 3];
                    } else {
#pragma unroll
                        for (int n = 0; n < 4; n++) mine[n] = acc[i][j][q * 4 + n];
                    }
#pragma unroll
                    for (int n = 0; n < 4; n++) {
                        float oth = __shfl_xor(mine[n], 1);
                        float tot = mine[n] + oth + bsv;
                        ssql[n] += tot * tot;
                        if (ev) out[(size_t)(rb + 8 * q + n) * F + f] = (bf16)tot;
                    }
                }
                // reduce over the 32-lane m32 group (pairs duplicate -> x0.5)
#pragma unroll
                for (int n = 0; n < 4; n++) {
                    float v = ssql[n];
                    v += __shfl_xor(v, 1); v += __shfl_xor(v, 2);
                    v += __shfl_xor(v, 4); v += __shfl_xor(v, 8);
                    v += __shfl_xor(v, 16);
                    ssql[n] = v;
                }
                if (m32 == 0) {
#pragma unroll
                    for (int n = 0; n < 4; n++)
                        atomicAdd(&ssq[rb + 8 * q + n], ssql[n] * 0.5f);
                }
            }
        }
    }
}

// ---------- apply L2-norm (from ssq) + ReLU, in place ----------------------
__global__ __launch_bounds__(256) void norm_apply(bf16x8* __restrict__ h,
                                                  const float* __restrict__ ssq,
                                                  int shift) {
    int idx = blockIdx.x * 256 + threadIdx.x;
    int row = idx >> shift;
    float inv = 1.f / fmaxf(sqrtf(ssq[row]), 1e-12f);
    bf16x8 v = h[idx], o;
#pragma unroll
    for (int c = 0; c < 8; c++) o[c] = (bf16)fmaxf((float)v[c] * inv, 0.f);
    h[idx] = o;
}

// ---------- final FC (1024 -> 10) + softmax, fused h4 norm+ReLU ------------
__global__ __launch_bounds__(256) void fc_softmax(const bf16x8* __restrict__ h,
                                                  const float* __restrict__ ssq4,
                                                  const float* __restrict__ Wfc,
                                                  const float* __restrict__ bfc,
                                                  float* __restrict__ outp) {
    __shared__ float WT[10][1024];
    int t = threadIdx.x;
    for (int i = t; i < 10240; i += 256) { int o = i % 10, k = i / 10; WT[o][k] = Wfc[i]; }
    __syncthreads();
    int wid = t >> 6, lane = t & 63;
    size_t e = (size_t)blockIdx.x * 4 + wid;
    const bf16x8* hp = h + e * 128;
    float acc[10];
#pragma unroll
    for (int o = 0; o < 10; o++) acc[o] = 0.f;
#pragma unroll
    for (int j = 0; j < 2; j++) {
        int ch = j * 64 + lane;
        int node = ch >> 5;                       // 32 chunks per 256-feat node row
        float inv = 1.f / fmaxf(sqrtf(ssq4[e * 4 + node]), 1e-12f);
        bf16x8 v = hp[ch];
        float f[8];
#pragma unroll
        for (int c = 0; c < 8; c++) f[c] = fmaxf((float)v[c] * inv, 0.f);
        int k0 = ch * 8;
#pragma unroll
        for (int o = 0; o < 10; o++) {
            const float* wr = &WT[o][k0];
            float s = 0.f;
#pragma unroll
            for (int c = 0; c < 8; c++) s += f[c] * wr[c];
            acc[o] += s;
        }
    }
#pragma unroll
    for (int o = 0; o < 10; o++) {
        float v = acc[o];
        v += __shfl_xor(v, 32); v += __shfl_xor(v, 16); v += __shfl_xor(v, 8);
        v += __shfl_xor(v, 4);  v += __shfl_xor(v, 2);  v += __shfl_xor(v, 1);
        acc[o] = v + bfc[o];
    }
    float mx = acc[0];
#pragma unroll
    for (int o = 1; o < 10; o++) mx = fmaxf(mx, acc[o]);
    float sum = 0.f, p[10];
#pragma unroll
    for (int o = 0; o < 10; o++) { p[o] = expf(acc[o] - mx); sum += p[o]; }
    float inv = 1.f / sum;
    if (lane < 10) outp[e * 10 + lane] = p[lane] * inv;
}

// ---------------------------------------------------------------------------
extern "C" void kernel_launch(void* const* d_in, const int* in_sizes, int n_in,
                              void* d_out, int out_size, void* d_ws, size_t ws_size,
                              hipStream_t stream) {
    const float* x   = (const float*)d_in[0];
    const int*   ei  = (const int*)d_in[1];
    const float* W1  = (const float*)d_in[2];
    const float* b1  = (const float*)d_in[3];
    const float* Wl2 = (const float*)d_in[4];
    const float* bl2 = (const float*)d_in[5];
    const float* Wr2 = (const float*)d_in[6];
    const float* Wl3 = (const float*)d_in[7];
    const float* bl3 = (const float*)d_in[8];
    const float* Wr3 = (const float*)d_in[9];
    const float* Wl4 = (const float*)d_in[10];
    const float* bl4 = (const float*)d_in[11];
    const float* Wr4 = (const float*)d_in[12];
    const float* Wfc = (const float*)d_in[13];
    const float* bfc = (const float*)d_in[14];
    float* out = (float*)d_out;

    const int B = 32768;
    char* base = (char*)d_ws;
    float* gmat = (float*)base;
    bf16* Wt1 = (bf16*)(base + 4096);                  // [1024 x 64]
    bf16* Wt2 = Wt1 + 1024 * 64;                       // [1024 x 1024] interleaved Wl2/Wr2
    bf16* Wt3 = Wt2 + 1024 * 1024;                     // [512 x 512]  interleaved
    bf16* Wt4 = Wt3 + 512 * 512;                       // [512 x 256]  interleaved
    char* sl  = (char*)(Wt4 + 512 * 256);
    size_t fixed = (size_t)(sl - base);

    // per-elem: R0 512B + R1 8192B + R2 4096B + ssq 48B = 12848 B
    int Bs = B;
    while (Bs > 512 && fixed + (size_t)Bs * 12848 > ws_size) Bs >>= 1;
    int nslice = B / Bs;
    int M = Bs * 4;

    bf16* R0 = (bf16*)sl;                       // xb  [M,64]
    bf16* R1 = R0 + (size_t)Bs * 256;           // h1 [M,1024]; then h3_un [M,256]
    bf16* R2 = R1 + (size_t)Bs * 4096;          // h2_un [M,512]; then h4_un [M,256]
    float* ssqb = (float*)(R2 + (size_t)Bs * 2048);   // 3*M floats

    hipLaunchKernelGGL(k_setup, dim3(1), dim3(64), 0, stream, ei, gmat);
    hipLaunchKernelGGL(wtrans, dim3((1024 * 64 + 255) / 256), dim3(256), 0, stream,
                       W1, 64, 1024, Wt1);
    hipLaunchKernelGGL(wtransI, dim3((1024 * 1024 + 255) / 256), dim3(256), 0, stream,
                       Wl2, Wr2, 1024, 512, Wt2);
    hipLaunchKernelGGL(wtransI, dim3((512 * 512 + 255) / 256), dim3(256), 0, stream,
                       Wl3, Wr3, 512, 256, Wt3);
    hipLaunchKernelGGL(wtransI, dim3((512 * 256 + 255) / 256), dim3(256), 0, stream,
                       Wl4, Wr4, 256, 256, Wt4);

    for (int s = 0; s < nslice; s++) {
        const float* xs = x + (size_t)s * Bs * 256;
        hipLaunchKernelGGL(k_zero, dim3((3 * M / 4 + 255) / 256), dim3(256), 0, stream,
                           (float4*)ssqb, 3 * M / 4);
        hipLaunchKernelGGL(cast_x, dim3(Bs / 8), dim3(256), 0, stream,
                           (const float4*)xs, (bf16x8*)R0);
        // L1 GCN: h1 = relu(mix(x@W1) + b1)   [mode 1]  N=1024, K=64
        hipLaunchKernelGGL(gemm_mfma, dim3(4, M / 128), dim3(256), 0, stream,
                           R0, 64, Wt1, b1, R1, 1024, 1, gmat, (float*)nullptr);
        // L2 SAGE: h2_un (F=512) + ssq  [mode 2]  N=1024, K=1024
        hipLaunchKernelGGL(gemm_mfma, dim3(4, M / 128), dim3(256), 0, stream,
                           R1, 1024, Wt2, bl2, R2, 1024, 2, gmat + 16, ssqb);
        hipLaunchKernelGGL(norm_apply, dim3(M / 4), dim3(256), 0, stream,
                           (bf16x8*)R2, ssqb, 6);
        // L3 SAGE: h3_un (F=256) into R1   N=512, K=512
        hipLaunchKernelGGL(gemm_mfma, dim3(2, M / 128), dim3(256), 0, stream,
                           R2, 512, Wt3, bl3, R1, 512, 2, gmat + 16, ssqb + M);
        hipLaunchKernelGGL(norm_apply, dim3(M / 8), dim3(256), 0, stream,
                           (bf16x8*)R1, ssqb + M, 5);
        // L4 SAGE: h4_un (F=256) into R2   N=512, K=256
        hipLaunchKernelGGL(gemm_mfma, dim3(2, M / 128), dim3(256), 0, stream,
                           R1, 256, Wt4, bl4, R2, 512, 2, gmat + 16, ssqb + 2 * M);
        // FC + softmax with fused h4 norm+ReLU
        hipLaunchKernelGGL(fc_softmax, dim3(Bs / 4), dim3(256), 0, stream,
                           (const bf16x8*)R2, ssqb + 2 * M, Wfc, bfc,
                           out + (size_t)s * Bs * 10);
    }
}